// Round 5
// baseline (327.352 us; speedup 1.0000x reference)
//
#include <hip/hip_runtime.h>
#include <math.h>

#define T 2048
#define D 512
#define NH 8
#define DH 64
#define NB 4
#define NTOK (NB * T)   // 8192
#define LOG2E 1.44269504f
#define QSCALE (0.125f * LOG2E)

using bf16x8 = __attribute__((ext_vector_type(8))) short;
using f32x4  = __attribute__((ext_vector_type(4))) float;

static __device__ __forceinline__ unsigned short f2bf(float f) {
    union { float f; unsigned u; } v; v.f = f;
    unsigned r = v.u + 0x7fffu + ((v.u >> 16) & 1u);   // RNE
    return (unsigned short)(r >> 16);
}
#if __has_builtin(__builtin_amdgcn_cvt_pk_bf16_f32)
static __device__ __forceinline__ unsigned pack_bf16_pair(float a, float b) {
    auto r = __builtin_amdgcn_cvt_pk_bf16_f32(a, b);
    union { decltype(r) v; unsigned u; } c; c.v = r;
    return c.u;
}
#else
static __device__ __forceinline__ unsigned pack_bf16_pair(float a, float b) {
    union { float f; unsigned u; } ua, ub; ua.f = a; ub.f = b;
    unsigned ra = ua.u + 0x7fffu + ((ua.u >> 16) & 1u);
    unsigned rb = ub.u + 0x7fffu + ((ub.u >> 16) & 1u);
    return __builtin_amdgcn_perm(rb, ra, 0x07060302);
}
#endif

// ---------------- Kernel A: LayerNorm + mask + scaled label bias ------------
__global__ __launch_bounds__(256) void ln_kernel(
    const float* __restrict__ embs, const float* __restrict__ labels,
    const float* __restrict__ g, const float* __restrict__ bb,
    const float* __restrict__ alpha_p, const float* __restrict__ beta_p,
    unsigned short* __restrict__ xb, float* __restrict__ wscaled,
    float* __restrict__ kpmf)
{
    __shared__ float sm[8], sm2[8];
    int n = blockIdx.x;
    int tid = threadIdx.x;
    int lane = tid & 63, wid = tid >> 6;
    const float* e = embs + (size_t)n * D;
    float v0 = e[tid], v1 = e[tid + 256];

    float s = v0 + v1, ss = v0 * v0 + v1 * v1;
    #pragma unroll
    for (int o = 32; o; o >>= 1) {
        s += __shfl_xor(s, o, 64);
        ss += __shfl_xor(ss, o, 64);
    }
    if (lane == 0) { sm[wid] = s; sm2[wid] = ss; }
    __syncthreads();
    float mu = (sm[0] + sm[1] + sm[2] + sm[3]) * (1.0f / D);
    float ex2 = (sm2[0] + sm2[1] + sm2[2] + sm2[3]) * (1.0f / D);
    float var = ex2 - mu * mu;
    float rstd = rsqrtf(var + 1e-5f);

    float x0 = (v0 - mu) * rstd * g[tid] + bb[tid];
    float x1 = (v1 - mu) * rstd * g[tid + 256] + bb[tid + 256];
    xb[(size_t)n * D + tid] = f2bf(x0);
    xb[(size_t)n * D + tid + 256] = f2bf(x1);

    __syncthreads();
    float as = fabsf(x0) + fabsf(x1);
    #pragma unroll
    for (int o = 32; o; o >>= 1) as += __shfl_xor(as, o, 64);
    if (lane == 0) sm[wid] = as;
    __syncthreads();
    if (tid == 0) {
        float abssum = sm[0] + sm[1] + sm[2] + sm[3];
        int kpm = (abssum <= 1e-6f);
        kpmf[n] = kpm ? 1.0f : 0.0f;
        wscaled[n] = kpm ? -3.0e38f
                         : (alpha_p[0] * labels[n] + beta_p[0]) * LOG2E;
    }
}

// ---------------- W -> bf16 conversion --------------------------------------
__global__ __launch_bounds__(256) void wconv_kernel(
    const float* __restrict__ w, unsigned short* __restrict__ wb)
{
    int i = (blockIdx.x * 256 + threadIdx.x) * 4;
    float4 f = *(const float4*)(w + i);
    ushort4 u;
    u.x = f2bf(f.x); u.y = f2bf(f.y); u.z = f2bf(f.z); u.w = f2bf(f.w);
    *(ushort4*)(wb + i) = u;
}

// ---------------- Kernel B: QKV projection, LDS-free MFMA -------------------
__global__ __launch_bounds__(256) void qkv_mfma(
    const unsigned short* __restrict__ xb, const unsigned short* __restrict__ wb,
    const float* __restrict__ bias, unsigned short* __restrict__ q,
    unsigned short* __restrict__ k, unsigned short* __restrict__ vt)
{
    int tid = threadIdx.x;
    int wave = tid >> 6, lane = tid & 63, quad = lane >> 4, lm = lane & 15;
    int wr = wave >> 1, wc = wave & 1;
    int m0 = blockIdx.x * 128 + wr * 64;
    int j0 = blockIdx.y * 128 + wc * 64;

    f32x4 acc[4][4];
    #pragma unroll
    for (int a = 0; a < 4; ++a)
        #pragma unroll
        for (int b = 0; b < 4; ++b) acc[a][b] = (f32x4){0.f,0.f,0.f,0.f};

    for (int kk = 0; kk < D; kk += 32) {
        bf16x8 af[4], bf[4];
        #pragma unroll
        for (int mf = 0; mf < 4; ++mf)
            af[mf] = *(const bf16x8*)(xb + (size_t)(m0 + mf * 16 + lm) * D + kk + quad * 8);
        #pragma unroll
        for (int nt = 0; nt < 4; ++nt)
            bf[nt] = *(const bf16x8*)(wb + (size_t)(j0 + nt * 16 + lm) * D + kk + quad * 8);
        #pragma unroll
        for (int mf = 0; mf < 4; ++mf)
            #pragma unroll
            for (int nt = 0; nt < 4; ++nt)
                acc[mf][nt] = __builtin_amdgcn_mfma_f32_16x16x32_bf16(af[mf], bf[nt], acc[mf][nt], 0, 0, 0);
    }

    #pragma unroll
    for (int nt = 0; nt < 4; ++nt) {
        int col = j0 + nt * 16 + lm;
        float bcol = bias[col];
        int part = col >> 9;           // 0=q,1=k,2=v
        int h = (col & 511) >> 6, dh = col & 63;
        #pragma unroll
        for (int mf = 0; mf < 4; ++mf) {
            #pragma unroll
            for (int r = 0; r < 4; ++r) {
                int tok = m0 + mf * 16 + quad * 4 + r;
                int b_ = tok >> 11, t = tok & (T - 1);
                int bh = b_ * NH + h;
                float val = acc[mf][nt][r] + bcol;
                if (part == 0)      q[((size_t)bh * T + t) * DH + dh] = f2bf(val * QSCALE);
                else if (part == 1) k[((size_t)bh * T + t) * DH + dh] = f2bf(val);
                else                vt[((size_t)bh * DH + dh) * T + t] = f2bf(val);
            }
        }
    }
}

// ---------------- Kernel C: flash attention, 2-way key split ---------------
// grid 1024: XCD-swizzled (bh co-located per XCD). Block = 128 queries x 1024
// keys of one bh. Writes partial O (f32) and partial l to global; additive
// across splits thanks to max-free exp2-domain softmax.
__global__ __launch_bounds__(256, 4) void attn_mfma(
    const unsigned short* __restrict__ q, const unsigned short* __restrict__ k,
    const unsigned short* __restrict__ vt, const float* __restrict__ wscaled,
    float* __restrict__ Opart, float* __restrict__ lpart)
{
    __shared__ __align__(16) unsigned short Ps[128][72];

    int g = blockIdx.x;
    int xcd = g & 7, local = g >> 3;
    int bh = xcd * 4 + (local >> 5);
    int r_ = local & 31;
    int q0 = (r_ >> 1) * 128;
    int ks = r_ & 1;

    int tid = threadIdx.x, wave = tid >> 6, lane = tid & 63;
    int quad = lane >> 4, lm = lane & 15;
    int b_ = bh >> 3;

    const unsigned short* qb = q + (size_t)bh * T * DH;
    const unsigned short* kb = k + (size_t)bh * T * DH;
    const unsigned short* vb = vt + (size_t)bh * DH * T;
    const float* wsb = wscaled + b_ * T;

    bf16x8 qf[2][2];
    #pragma unroll
    for (int mf = 0; mf < 2; ++mf)
        #pragma unroll
        for (int kk = 0; kk < 2; ++kk)
            qf[mf][kk] = *(const bf16x8*)(qb + (size_t)(q0 + wave * 32 + mf * 16 + lm) * DH + kk * 32 + quad * 8);

    f32x4 accO[2][4];
    float l_part[2][4];
    #pragma unroll
    for (int mf = 0; mf < 2; ++mf)
        #pragma unroll
        for (int nt = 0; nt < 4; ++nt) accO[mf][nt] = (f32x4){0.f,0.f,0.f,0.f};
    #pragma unroll
    for (int mf = 0; mf < 2; ++mf)
        #pragma unroll
        for (int r = 0; r < 4; ++r) l_part[mf][r] = 0.f;

    int jbeg = ks * (T / 2), jend = jbeg + (T / 2);
    for (int j0t = jbeg; j0t < jend; j0t += 64) {
        bf16x8 kf[4][2];
        float bias[4];
        #pragma unroll
        for (int nt = 0; nt < 4; ++nt) {
            int key = j0t + lm * 4 + nt;
            #pragma unroll
            for (int kk = 0; kk < 2; ++kk)
                kf[nt][kk] = *(const bf16x8*)(kb + (size_t)key * DH + kk * 32 + quad * 8);
            bias[nt] = wsb[key];
        }

        f32x4 s[2][4];
        #pragma unroll
        for (int mf = 0; mf < 2; ++mf)
            #pragma unroll
            for (int nt = 0; nt < 4; ++nt) {
                f32x4 t0 = (f32x4){0.f,0.f,0.f,0.f};
                t0 = __builtin_amdgcn_mfma_f32_16x16x32_bf16(qf[mf][0], kf[nt][0], t0, 0, 0, 0);
                t0 = __builtin_amdgcn_mfma_f32_16x16x32_bf16(qf[mf][1], kf[nt][1], t0, 0, 0, 0);
                s[mf][nt] = t0;
            }

        #pragma unroll
        for (int mf = 0; mf < 2; ++mf) {
            int rowb = wave * 32 + mf * 16 + quad * 4;
            #pragma unroll
            for (int r = 0; r < 4; ++r) {
                float p0 = __builtin_amdgcn_exp2f(s[mf][0][r] + bias[0]);
                float p1 = __builtin_amdgcn_exp2f(s[mf][1][r] + bias[1]);
                float p2 = __builtin_amdgcn_exp2f(s[mf][2][r] + bias[2]);
                float p3 = __builtin_amdgcn_exp2f(s[mf][3][r] + bias[3]);
                l_part[mf][r] += (p0 + p1) + (p2 + p3);
                uint2 pw;
                pw.x = pack_bf16_pair(p0, p1);
                pw.y = pack_bf16_pair(p2, p3);
                *(uint2*)&Ps[rowb + r][lm * 4] = pw;
            }
        }

        bf16x8 vf[4][2], pf[2][2];
        #pragma unroll
        for (int nt = 0; nt < 4; ++nt)
            #pragma unroll
            for (int kk = 0; kk < 2; ++kk)
                vf[nt][kk] = *(const bf16x8*)(vb + (size_t)(nt * 16 + lm) * T + j0t + kk * 32 + quad * 8);
        #pragma unroll
        for (int mf = 0; mf < 2; ++mf)
            #pragma unroll
            for (int kk = 0; kk < 2; ++kk)
                pf[mf][kk] = *(const bf16x8*)&Ps[wave * 32 + mf * 16 + lm][kk * 32 + quad * 8];

        #pragma unroll
        for (int mf = 0; mf < 2; ++mf)
            #pragma unroll
            for (int nt = 0; nt < 4; ++nt) {
                accO[mf][nt] = __builtin_amdgcn_mfma_f32_16x16x32_bf16(pf[mf][0], vf[nt][0], accO[mf][nt], 0, 0, 0);
                accO[mf][nt] = __builtin_amdgcn_mfma_f32_16x16x32_bf16(pf[mf][1], vf[nt][1], accO[mf][nt], 0, 0, 0);
            }
    }

    // reduce l across the 16 col-owning lanes (lane bits 0..3)
    #pragma unroll
    for (int mf = 0; mf < 2; ++mf)
        #pragma unroll
        for (int r = 0; r < 4; ++r) {
            float lv = l_part[mf][r];
            #pragma unroll
            for (int off = 1; off <= 8; off <<= 1) lv += __shfl_xor(lv, off, 64);
            l_part[mf][r] = lv;
        }

    size_t obase = (((size_t)ks * 32 + bh) * T + q0) * DH;
    size_t lbase = ((size_t)ks * 32 + bh) * T + q0;
    #pragma unroll
    for (int mf = 0; mf < 2; ++mf)
        #pragma unroll
        for (int r = 0; r < 4; ++r) {
            int row = wave * 32 + mf * 16 + quad * 4 + r;
            #pragma unroll
            for (int nt = 0; nt < 4; ++nt)
                Opart[obase + (size_t)row * DH + nt * 16 + lm] = accO[mf][nt][r];
        }
    if (lm == 0) {
        #pragma unroll
        for (int mf = 0; mf < 2; ++mf)
            #pragma unroll
            for (int r = 0; r < 4; ++r)
                lpart[lbase + wave * 32 + mf * 16 + quad * 4 + r] = l_part[mf][r];
    }
}

// ---------------- Kernel D: combine splits + masked pooling -----------------
__global__ __launch_bounds__(256) void combine_pool(
    const float* __restrict__ Opart, const float* __restrict__ lpart,
    const float* __restrict__ kpmf, float* __restrict__ S)
{
    __shared__ float sm[4][64];
    int bh = blockIdx.x;
    int b_ = bh >> 3, h = bh & 7;
    int lane = threadIdx.x & 63, chunk = threadIdx.x >> 6;
    const float* O0 = Opart + (size_t)bh * T * DH;
    const float* O1 = Opart + ((size_t)32 + bh) * T * DH;
    const float* l0 = lpart + (size_t)bh * T;
    const float* l1 = lpart + ((size_t)32 + bh) * T;
    const float* kp = kpmf + b_ * T;

    float acc = 0.f;
    for (int i = 0; i < 512; ++i) {
        int t = chunk * 512 + i;
        float l = l0[t] + l1[t];
        float w = (1.0f - kp[t]) / fmaxf(l, 1e-37f);
        acc += (O0[(size_t)t * DH + lane] + O1[(size_t)t * DH + lane]) * w;
    }
    sm[chunk][lane] = acc;
    __syncthreads();
    if (chunk == 0)
        S[b_ * D + h * DH + lane] = sm[0][lane] + sm[1][lane] + sm[2][lane] + sm[3][lane];
}

// ---------------- Kernel E: out-projection of pooled vector + bias ----------
__global__ __launch_bounds__(256) void out_kernel(
    const float* __restrict__ S, const float* __restrict__ kpmf,
    const float* __restrict__ Wo, const float* __restrict__ bo,
    float* __restrict__ out)
{
    __shared__ float Sl[512];
    __shared__ float cs[4];
    __shared__ float pr[4][64];
    int b_ = blockIdx.x >> 3;
    int cg = blockIdx.x & 7;
    int tid = threadIdx.x;
    int col = tid & 63, kq = tid >> 6;
    Sl[tid] = S[b_ * D + tid];
    Sl[tid + 256] = S[b_ * D + tid + 256];
    const float* kp = kpmf + b_ * T;
    float c = 0.f;
    for (int t = tid; t < T; t += 256) c += kp[t];
    #pragma unroll
    for (int o = 32; o; o >>= 1) c += __shfl_xor(c, o, 64);
    if ((tid & 63) == 0) cs[tid >> 6] = c;
    __syncthreads();
    float masked = cs[0] + cs[1] + cs[2] + cs[3];
    float cnt = (float)T - masked;
    float inv = 1.0f / fmaxf(cnt, 1.0f);

    int d = cg * 64 + col;
    const float4* wr4 = (const float4*)(Wo + (size_t)d * D + kq * 128);
    float dot = 0.f;
    #pragma unroll 8
    for (int i = 0; i < 32; ++i) {
        float4 w4 = wr4[i];
        int kbase = kq * 128 + i * 4;
        dot += Sl[kbase + 0] * w4.x + Sl[kbase + 1] * w4.y +
               Sl[kbase + 2] * w4.z + Sl[kbase + 3] * w4.w;
    }
    pr[kq][col] = dot;
    __syncthreads();
    if (kq == 0) {
        float tot = pr[0][col] + pr[1][col] + pr[2][col] + pr[3][col];
        out[b_ * D + d] = (tot + bo[d] * cnt) * inv;
    }
}

extern "C" void kernel_launch(void* const* d_in, const int* in_sizes, int n_in,
                              void* d_out, int out_size, void* d_ws, size_t ws_size,
                              hipStream_t stream) {
    const float* embs   = (const float*)d_in[0];
    const float* labels = (const float*)d_in[1];
    const float* ln_g   = (const float*)d_in[2];
    const float* ln_b   = (const float*)d_in[3];
    const float* ipw    = (const float*)d_in[4];
    const float* ipb    = (const float*)d_in[5];
    const float* ow     = (const float*)d_in[6];
    const float* obb    = (const float*)d_in[7];
    const float* alpha  = (const float*)d_in[8];
    const float* beta   = (const float*)d_in[9];
    float* out = (float*)d_out;

    unsigned short* xb = (unsigned short*)d_ws;          // 8192*512 bf16
    unsigned short* wb = xb + (size_t)NTOK * D;          // 1536*512 bf16
    unsigned short* q  = wb + (size_t)3 * D * D;         // 8192*512 bf16
    unsigned short* k  = q  + (size_t)NTOK * D;
    unsigned short* vt = k  + (size_t)NTOK * D;
    float* Opart   = (float*)(vt + (size_t)NTOK * D);    // 2*32*2048*64 f32
    float* lpart   = Opart + (size_t)2 * 32 * T * DH;    // 2*32*2048 f32
    float* wscaled = lpart + (size_t)2 * 32 * T;         // 8192 f32
    float* kpmf    = wscaled + NTOK;                     // 8192
    float* S       = kpmf + NTOK;                        // 2048

    ln_kernel<<<NTOK, 256, 0, stream>>>(embs, labels, ln_g, ln_b, alpha, beta,
                                        xb, wscaled, kpmf);
    wconv_kernel<<<(3 * D * D) / 1024, 256, 0, stream>>>(ipw, wb);
    dim3 gq(NTOK / 128, (3 * D) / 128);
    qkv_mfma<<<gq, 256, 0, stream>>>(xb, wb, ipb, q, k, vt);
    attn_mfma<<<1024, 256, 0, stream>>>(q, k, vt, wscaled, Opart, lpart);
    combine_pool<<<NB * NH, 256, 0, stream>>>(Opart, lpart, kpmf, S);
    out_kernel<<<NB * 8, 256, 0, stream>>>(S, kpmf, ow, obb, out);
}

// Round 6
// 284.259 us; speedup vs baseline: 1.1516x; 1.1516x over previous
//
#include <hip/hip_runtime.h>
#include <math.h>

#define T 2048
#define D 512
#define NH 8
#define DH 64
#define NB 4
#define NTOK (NB * T)   // 8192
#define LOG2E 1.44269504f
#define QSCALE (0.125f * LOG2E)

using bf16x8 = __attribute__((ext_vector_type(8))) short;
using f32x4  = __attribute__((ext_vector_type(4))) float;

static __device__ __forceinline__ unsigned short f2bf(float f) {
    union { float f; unsigned u; } v; v.f = f;
    unsigned r = v.u + 0x7fffu + ((v.u >> 16) & 1u);   // RNE
    return (unsigned short)(r >> 16);
}
#if __has_builtin(__builtin_amdgcn_cvt_pk_bf16_f32)
static __device__ __forceinline__ unsigned pack_bf16_pair(float a, float b) {
    auto r = __builtin_amdgcn_cvt_pk_bf16_f32(a, b);
    union { decltype(r) v; unsigned u; } c; c.v = r;
    return c.u;
}
#else
static __device__ __forceinline__ unsigned pack_bf16_pair(float a, float b) {
    union { float f; unsigned u; } ua, ub; ua.f = a; ub.f = b;
    unsigned ra = ua.u + 0x7fffu + ((ua.u >> 16) & 1u);
    unsigned rb = ub.u + 0x7fffu + ((ub.u >> 16) & 1u);
    return __builtin_amdgcn_perm(rb, ra, 0x07060302);
}
#endif

// ---------------- Kernel A: LayerNorm, wave-per-token (no LDS/barriers) -----
__global__ __launch_bounds__(256) void ln_kernel(
    const float* __restrict__ embs, const float* __restrict__ labels,
    const float* __restrict__ g, const float* __restrict__ bb,
    const float* __restrict__ alpha_p, const float* __restrict__ beta_p,
    unsigned short* __restrict__ xb, float* __restrict__ wscaled,
    float* __restrict__ kpmf)
{
    int n = blockIdx.x * 4 + (threadIdx.x >> 6);
    int lane = threadIdx.x & 63;
    const float* e = embs + (size_t)n * D + lane * 8;
    float4 a4 = *(const float4*)e, b4 = *(const float4*)(e + 4);
    float v[8] = {a4.x, a4.y, a4.z, a4.w, b4.x, b4.y, b4.z, b4.w};

    float s = 0.f, ss = 0.f;
    #pragma unroll
    for (int j = 0; j < 8; ++j) { s += v[j]; ss += v[j] * v[j]; }
    #pragma unroll
    for (int o = 1; o <= 32; o <<= 1) {
        s += __shfl_xor(s, o, 64);
        ss += __shfl_xor(ss, o, 64);
    }
    float mu = s * (1.0f / D);
    float var = ss * (1.0f / D) - mu * mu;
    float rstd = rsqrtf(var + 1e-5f);

    float4 g0 = *(const float4*)(g + lane * 8), g1 = *(const float4*)(g + lane * 8 + 4);
    float4 c0 = *(const float4*)(bb + lane * 8), c1 = *(const float4*)(bb + lane * 8 + 4);
    float gv[8] = {g0.x, g0.y, g0.z, g0.w, g1.x, g1.y, g1.z, g1.w};
    float cv[8] = {c0.x, c0.y, c0.z, c0.w, c1.x, c1.y, c1.z, c1.w};

    float x[8], as = 0.f;
    #pragma unroll
    for (int j = 0; j < 8; ++j) {
        x[j] = (v[j] - mu) * rstd * gv[j] + cv[j];
        as += fabsf(x[j]);
    }
    uint4 pk;
    pk.x = pack_bf16_pair(x[0], x[1]);
    pk.y = pack_bf16_pair(x[2], x[3]);
    pk.z = pack_bf16_pair(x[4], x[5]);
    pk.w = pack_bf16_pair(x[6], x[7]);
    *(uint4*)(xb + (size_t)n * D + lane * 8) = pk;

    #pragma unroll
    for (int o = 1; o <= 32; o <<= 1) as += __shfl_xor(as, o, 64);
    if (lane == 0) {
        int kpm = (as <= 1e-6f);
        kpmf[n] = kpm ? 1.0f : 0.0f;
        wscaled[n] = kpm ? -3.0e38f
                         : (alpha_p[0] * labels[n] + beta_p[0]) * LOG2E;
    }
}

// ---------------- W -> bf16 conversion --------------------------------------
__global__ __launch_bounds__(256) void wconv_kernel(
    const float* __restrict__ w, unsigned short* __restrict__ wb)
{
    int i = (blockIdx.x * 256 + threadIdx.x) * 4;
    float4 f = *(const float4*)(w + i);
    ushort2 lo = {f2bf(f.x), f2bf(f.y)};
    ushort2 hi = {f2bf(f.z), f2bf(f.w)};
    *(ushort2*)(wb + i) = lo;
    *(ushort2*)(wb + i + 2) = hi;
}

// ---------------- Kernel B: QKV projection, LDS-free MFMA, pipelined --------
__global__ __launch_bounds__(256) void qkv_mfma(
    const unsigned short* __restrict__ xb, const unsigned short* __restrict__ wb,
    const float* __restrict__ bias, unsigned short* __restrict__ q,
    unsigned short* __restrict__ k, unsigned short* __restrict__ vt)
{
    int tid = threadIdx.x;
    int wave = tid >> 6, lane = tid & 63, quad = lane >> 4, lm = lane & 15;
    int wr = wave >> 1, wc = wave & 1;
    int m0 = blockIdx.x * 128 + wr * 64;
    int j0 = blockIdx.y * 128 + wc * 64;

    f32x4 acc[4][4];
    #pragma unroll
    for (int a = 0; a < 4; ++a)
        #pragma unroll
        for (int b = 0; b < 4; ++b) acc[a][b] = (f32x4){0.f,0.f,0.f,0.f};

    bf16x8 af0[4], bf0[4], af1[4], bf1[4];

    auto load_ab = [&](int kk, bf16x8 (&af)[4], bf16x8 (&bf)[4]) {
        #pragma unroll
        for (int mf = 0; mf < 4; ++mf)
            af[mf] = *(const bf16x8*)(xb + (size_t)(m0 + mf * 16 + lm) * D + kk + quad * 8);
        #pragma unroll
        for (int nt = 0; nt < 4; ++nt)
            bf[nt] = *(const bf16x8*)(wb + (size_t)(j0 + nt * 16 + lm) * D + kk + quad * 8);
    };
    auto do_mfma = [&](bf16x8 (&af)[4], bf16x8 (&bf)[4]) {
        #pragma unroll
        for (int mf = 0; mf < 4; ++mf)
            #pragma unroll
            for (int nt = 0; nt < 4; ++nt)
                acc[mf][nt] = __builtin_amdgcn_mfma_f32_16x16x32_bf16(af[mf], bf[nt], acc[mf][nt], 0, 0, 0);
    };

    load_ab(0, af0, bf0);
    for (int kk = 0; kk < D; kk += 64) {
        load_ab(kk + 32, af1, bf1);
        do_mfma(af0, bf0);
        int kn = (kk + 64 < D) ? kk + 64 : 0;   // phantom reload of 0 on last iter
        load_ab(kn, af0, bf0);
        do_mfma(af1, bf1);
    }

    #pragma unroll
    for (int nt = 0; nt < 4; ++nt) {
        int col = j0 + nt * 16 + lm;
        float bcol = bias[col];
        int part = col >> 9;           // 0=q,1=k,2=v
        int h = (col & 511) >> 6, dh = col & 63;
        #pragma unroll
        for (int mf = 0; mf < 4; ++mf) {
            #pragma unroll
            for (int r = 0; r < 4; ++r) {
                int tok = m0 + mf * 16 + quad * 4 + r;
                int b_ = tok >> 11, t = tok & (T - 1);
                int bh = b_ * NH + h;
                float val = acc[mf][nt][r] + bcol;
                if (part == 0)      q[((size_t)bh * T + t) * DH + dh] = f2bf(val * QSCALE);
                else if (part == 1) k[((size_t)bh * T + t) * DH + dh] = f2bf(val);
                else                vt[((size_t)bh * DH + dh) * T + t] = f2bf(val);
            }
        }
    }
}

// ---------------- Kernel C: flash attention, pipelined, 2-way key split -----
__global__ __launch_bounds__(256) void attn_mfma(
    const unsigned short* __restrict__ q, const unsigned short* __restrict__ k,
    const unsigned short* __restrict__ vt, const float* __restrict__ wscaled,
    float* __restrict__ Opart, float* __restrict__ lpart)
{
    __shared__ __align__(16) unsigned short Ps[128][72];

    int g = blockIdx.x;
    int xcd = g & 7, local = g >> 3;
    int bh = xcd * 4 + (local >> 5);
    int r_ = local & 31;
    int q0 = (r_ >> 1) * 128;
    int ks = r_ & 1;

    int tid = threadIdx.x, wave = tid >> 6, lane = tid & 63;
    int quad = lane >> 4, lm = lane & 15;
    int b_ = bh >> 3;

    const unsigned short* qb = q + (size_t)bh * T * DH;
    const unsigned short* kb = k + (size_t)bh * T * DH;
    const unsigned short* vb = vt + (size_t)bh * DH * T;
    const float* wsb = wscaled + b_ * T;

    bf16x8 qf[2][2];
    #pragma unroll
    for (int mf = 0; mf < 2; ++mf)
        #pragma unroll
        for (int kk = 0; kk < 2; ++kk)
            qf[mf][kk] = *(const bf16x8*)(qb + (size_t)(q0 + wave * 32 + mf * 16 + lm) * DH + kk * 32 + quad * 8);

    f32x4 accO[2][4];
    float l_part[2][4];
    #pragma unroll
    for (int mf = 0; mf < 2; ++mf)
        #pragma unroll
        for (int nt = 0; nt < 4; ++nt) accO[mf][nt] = (f32x4){0.f,0.f,0.f,0.f};
    #pragma unroll
    for (int mf = 0; mf < 2; ++mf)
        #pragma unroll
        for (int r = 0; r < 4; ++r) l_part[mf][r] = 0.f;

    bf16x8 kf0[4][2], kf1[4][2];
    float4 b40, b41;

    auto load_k = [&](int j0t, bf16x8 (&kf)[4][2], float4& b4) {
        #pragma unroll
        for (int nt = 0; nt < 4; ++nt) {
            const unsigned short* kp_ = kb + (size_t)(j0t + lm * 4 + nt) * DH + quad * 8;
            kf[nt][0] = *(const bf16x8*)kp_;
            kf[nt][1] = *(const bf16x8*)(kp_ + 32);
        }
        b4 = *(const float4*)(wsb + j0t + lm * 4);
    };

    auto process = [&](int j0t, bf16x8 (&kf)[4][2], float4 b4) {
        // V loads first: latency hides under QK MFMA + exp2 + LDS write
        bf16x8 vf[4][2];
        #pragma unroll
        for (int nt = 0; nt < 4; ++nt) {
            const unsigned short* vp = vb + (size_t)(nt * 16 + lm) * T + j0t + quad * 8;
            vf[nt][0] = *(const bf16x8*)vp;
            vf[nt][1] = *(const bf16x8*)(vp + 32);
        }

        f32x4 s[2][4];
        #pragma unroll
        for (int mf = 0; mf < 2; ++mf)
            #pragma unroll
            for (int nt = 0; nt < 4; ++nt) {
                f32x4 t0 = (f32x4){0.f,0.f,0.f,0.f};
                t0 = __builtin_amdgcn_mfma_f32_16x16x32_bf16(qf[mf][0], kf[nt][0], t0, 0, 0, 0);
                t0 = __builtin_amdgcn_mfma_f32_16x16x32_bf16(qf[mf][1], kf[nt][1], t0, 0, 0, 0);
                s[mf][nt] = t0;
            }

        float bias[4] = {b4.x, b4.y, b4.z, b4.w};
        #pragma unroll
        for (int mf = 0; mf < 2; ++mf) {
            int rowb = wave * 32 + mf * 16 + quad * 4;
            #pragma unroll
            for (int r = 0; r < 4; ++r) {
                float p0 = __builtin_amdgcn_exp2f(s[mf][0][r] + bias[0]);
                float p1 = __builtin_amdgcn_exp2f(s[mf][1][r] + bias[1]);
                float p2 = __builtin_amdgcn_exp2f(s[mf][2][r] + bias[2]);
                float p3 = __builtin_amdgcn_exp2f(s[mf][3][r] + bias[3]);
                l_part[mf][r] += (p0 + p1) + (p2 + p3);
                uint2 pw;
                pw.x = pack_bf16_pair(p0, p1);
                pw.y = pack_bf16_pair(p2, p3);
                *(uint2*)&Ps[rowb + r][lm * 4] = pw;
            }
        }

        bf16x8 pf[2][2];
        #pragma unroll
        for (int mf = 0; mf < 2; ++mf)
            #pragma unroll
            for (int kk = 0; kk < 2; ++kk)
                pf[mf][kk] = *(const bf16x8*)&Ps[wave * 32 + mf * 16 + lm][kk * 32 + quad * 8];

        #pragma unroll
        for (int mf = 0; mf < 2; ++mf)
            #pragma unroll
            for (int nt = 0; nt < 4; ++nt) {
                accO[mf][nt] = __builtin_amdgcn_mfma_f32_16x16x32_bf16(pf[mf][0], vf[nt][0], accO[mf][nt], 0, 0, 0);
                accO[mf][nt] = __builtin_amdgcn_mfma_f32_16x16x32_bf16(pf[mf][1], vf[nt][1], accO[mf][nt], 0, 0, 0);
            }
    };

    int jbeg = ks * (T / 2), jend = jbeg + (T / 2);
    load_k(jbeg, kf0, b40);
    for (int j0t = jbeg; j0t < jend; j0t += 128) {
        load_k(j0t + 64, kf1, b41);
        process(j0t, kf0, b40);
        int jn = (j0t + 128 < jend) ? j0t + 128 : jbeg;  // phantom reload on last
        load_k(jn, kf0, b40);
        process(j0t + 64, kf1, b41);
    }

    #pragma unroll
    for (int mf = 0; mf < 2; ++mf)
        #pragma unroll
        for (int r = 0; r < 4; ++r) {
            float lv = l_part[mf][r];
            #pragma unroll
            for (int off = 1; off <= 8; off <<= 1) lv += __shfl_xor(lv, off, 64);
            l_part[mf][r] = lv;
        }

    size_t obase = (((size_t)ks * 32 + bh) * T + q0) * DH;
    size_t lbase = ((size_t)ks * 32 + bh) * T + q0;
    #pragma unroll
    for (int mf = 0; mf < 2; ++mf)
        #pragma unroll
        for (int r = 0; r < 4; ++r) {
            int row = wave * 32 + mf * 16 + quad * 4 + r;
            #pragma unroll
            for (int nt = 0; nt < 4; ++nt)
                Opart[obase + (size_t)row * DH + nt * 16 + lm] = accO[mf][nt][r];
        }
    if (lm == 0) {
        #pragma unroll
        for (int mf = 0; mf < 2; ++mf)
            #pragma unroll
            for (int r = 0; r < 4; ++r)
                lpart[lbase + wave * 32 + mf * 16 + quad * 4 + r] = l_part[mf][r];
    }
}

// ---------------- Kernel D: combine splits + masked pooling (256 blocks) ----
__global__ __launch_bounds__(256) void combine_pool(
    const float* __restrict__ Opart, const float* __restrict__ lpart,
    const float* __restrict__ kpmf, float* __restrict__ S)
{
    __shared__ float sm[4][64];
    int bh = blockIdx.x & 31;
    int seg = blockIdx.x >> 5;       // 0..7
    int b_ = bh >> 3, h = bh & 7;
    int lane = threadIdx.x & 63, chunk = threadIdx.x >> 6;
    const float* O0 = Opart + (size_t)bh * T * DH;
    const float* O1 = Opart + ((size_t)32 + bh) * T * DH;
    const float* l0 = lpart + (size_t)bh * T;
    const float* l1 = lpart + ((size_t)32 + bh) * T;
    const float* kp = kpmf + b_ * T;

    int t0 = seg * 256 + chunk * 64;
    float acc = 0.f;
    for (int i = 0; i < 64; ++i) {
        int t = t0 + i;
        float l = l0[t] + l1[t];
        float w = (1.0f - kp[t]) / fmaxf(l, 1e-37f);
        acc += (O0[(size_t)t * DH + lane] + O1[(size_t)t * DH + lane]) * w;
    }
    sm[chunk][lane] = acc;
    __syncthreads();
    if (chunk == 0)
        atomicAdd(&S[b_ * D + h * DH + lane],
                  sm[0][lane] + sm[1][lane] + sm[2][lane] + sm[3][lane]);
}

// ---------------- Kernel E: out-projection of pooled vector + bias ----------
__global__ __launch_bounds__(256) void out_kernel(
    const float* __restrict__ S, const float* __restrict__ kpmf,
    const float* __restrict__ Wo, const float* __restrict__ bo,
    float* __restrict__ out)
{
    __shared__ float Sl[512];
    __shared__ float cs[4];
    __shared__ float pr[4][64];
    int b_ = blockIdx.x >> 3;
    int cg = blockIdx.x & 7;
    int tid = threadIdx.x;
    int col = tid & 63, kq = tid >> 6;
    Sl[tid] = S[b_ * D + tid];
    Sl[tid + 256] = S[b_ * D + tid + 256];
    const float* kp = kpmf + b_ * T;
    float c = 0.f;
    for (int t = tid; t < T; t += 256) c += kp[t];
    #pragma unroll
    for (int o = 32; o; o >>= 1) c += __shfl_xor(c, o, 64);
    if ((tid & 63) == 0) cs[tid >> 6] = c;
    __syncthreads();
    float masked = cs[0] + cs[1] + cs[2] + cs[3];
    float cnt = (float)T - masked;
    float inv = 1.0f / fmaxf(cnt, 1.0f);

    int d = cg * 64 + col;
    const float4* wr4 = (const float4*)(Wo + (size_t)d * D + kq * 128);
    float dot = 0.f;
    #pragma unroll 8
    for (int i = 0; i < 32; ++i) {
        float4 w4 = wr4[i];
        int kbase = kq * 128 + i * 4;
        dot += Sl[kbase + 0] * w4.x + Sl[kbase + 1] * w4.y +
               Sl[kbase + 2] * w4.z + Sl[kbase + 3] * w4.w;
    }
    pr[kq][col] = dot;
    __syncthreads();
    if (kq == 0) {
        float tot = pr[0][col] + pr[1][col] + pr[2][col] + pr[3][col];
        out[b_ * D + d] = (tot + bo[d] * cnt) * inv;
    }
}

extern "C" void kernel_launch(void* const* d_in, const int* in_sizes, int n_in,
                              void* d_out, int out_size, void* d_ws, size_t ws_size,
                              hipStream_t stream) {
    const float* embs   = (const float*)d_in[0];
    const float* labels = (const float*)d_in[1];
    const float* ln_g   = (const float*)d_in[2];
    const float* ln_b   = (const float*)d_in[3];
    const float* ipw    = (const float*)d_in[4];
    const float* ipb    = (const float*)d_in[5];
    const float* ow     = (const float*)d_in[6];
    const float* obb    = (const float*)d_in[7];
    const float* alpha  = (const float*)d_in[8];
    const float* beta   = (const float*)d_in[9];
    float* out = (float*)d_out;

    unsigned short* xb = (unsigned short*)d_ws;          // 8192*512 bf16
    unsigned short* wb = xb + (size_t)NTOK * D;          // 1536*512 bf16
    unsigned short* q  = wb + (size_t)3 * D * D;         // 8192*512 bf16
    unsigned short* k  = q  + (size_t)NTOK * D;
    unsigned short* vt = k  + (size_t)NTOK * D;
    float* Opart   = (float*)(vt + (size_t)NTOK * D);    // 2*32*2048*64 f32
    float* lpart   = Opart + (size_t)2 * 32 * T * DH;    // 2*32*2048 f32
    float* wscaled = lpart + (size_t)2 * 32 * T;         // 8192 f32
    float* kpmf    = wscaled + NTOK;                     // 8192
    float* S       = kpmf + NTOK;                        // 2048

    hipMemsetAsync(S, 0, (size_t)NB * D * sizeof(float), stream);
    ln_kernel<<<NTOK / 4, 256, 0, stream>>>(embs, labels, ln_g, ln_b, alpha, beta,
                                            xb, wscaled, kpmf);
    wconv_kernel<<<(3 * D * D) / 1024, 256, 0, stream>>>(ipw, wb);
    dim3 gq(NTOK / 128, (3 * D) / 128);
    qkv_mfma<<<gq, 256, 0, stream>>>(xb, wb, ipb, q, k, vt);
    attn_mfma<<<1024, 256, 0, stream>>>(q, k, vt, wscaled, Opart, lpart);
    combine_pool<<<256, 256, 0, stream>>>(Opart, lpart, kpmf, S);
    out_kernel<<<NB * 8, 256, 0, stream>>>(S, kpmf, ow, obb, out);
}

// Round 7
// 210.648 us; speedup vs baseline: 1.5540x; 1.3494x over previous
//
#include <hip/hip_runtime.h>
#include <math.h>

#define T 2048
#define D 512
#define NH 8
#define DH 64
#define NB 4
#define NTOK (NB * T)   // 8192
#define LOG2E 1.44269504f
#define QSCALE (0.125f * LOG2E)

using bf16x8 = __attribute__((ext_vector_type(8))) short;
using f32x4  = __attribute__((ext_vector_type(4))) float;

static __device__ __forceinline__ unsigned short f2bf(float f) {
    union { float f; unsigned u; } v; v.f = f;
    unsigned r = v.u + 0x7fffu + ((v.u >> 16) & 1u);   // RNE
    return (unsigned short)(r >> 16);
}
#if __has_builtin(__builtin_amdgcn_cvt_pk_bf16_f32)
static __device__ __forceinline__ unsigned pack_bf16_pair(float a, float b) {
    auto r = __builtin_amdgcn_cvt_pk_bf16_f32(a, b);
    union { decltype(r) v; unsigned u; } c; c.v = r;
    return c.u;
}
#else
static __device__ __forceinline__ unsigned pack_bf16_pair(float a, float b) {
    union { float f; unsigned u; } ua, ub; ua.f = a; ub.f = b;
    unsigned ra = ua.u + 0x7fffu + ((ua.u >> 16) & 1u);
    unsigned rb = ub.u + 0x7fffu + ((ub.u >> 16) & 1u);
    return __builtin_amdgcn_perm(rb, ra, 0x07060302);
}
#endif

// ---------------- Kernel A: LayerNorm, wave-per-token -----------------------
// Emits x (bf16, row-major), wexp[n] = exp(alpha*label+beta) or 0 if masked,
// kpmf[n] = mask flag.
__global__ __launch_bounds__(256) void ln_kernel(
    const float* __restrict__ embs, const float* __restrict__ labels,
    const float* __restrict__ g, const float* __restrict__ bb,
    const float* __restrict__ alpha_p, const float* __restrict__ beta_p,
    unsigned short* __restrict__ xb, float* __restrict__ wexp,
    float* __restrict__ kpmf)
{
    int n = blockIdx.x * 4 + (threadIdx.x >> 6);
    int lane = threadIdx.x & 63;
    const float* e = embs + (size_t)n * D + lane * 8;
    float4 a4 = *(const float4*)e, b4 = *(const float4*)(e + 4);
    float v[8] = {a4.x, a4.y, a4.z, a4.w, b4.x, b4.y, b4.z, b4.w};

    float s = 0.f, ss = 0.f;
    #pragma unroll
    for (int j = 0; j < 8; ++j) { s += v[j]; ss += v[j] * v[j]; }
    #pragma unroll
    for (int o = 1; o <= 32; o <<= 1) {
        s += __shfl_xor(s, o, 64);
        ss += __shfl_xor(ss, o, 64);
    }
    float mu = s * (1.0f / D);
    float var = ss * (1.0f / D) - mu * mu;
    float rstd = rsqrtf(var + 1e-5f);

    float4 g0 = *(const float4*)(g + lane * 8), g1 = *(const float4*)(g + lane * 8 + 4);
    float4 c0 = *(const float4*)(bb + lane * 8), c1 = *(const float4*)(bb + lane * 8 + 4);
    float gv[8] = {g0.x, g0.y, g0.z, g0.w, g1.x, g1.y, g1.z, g1.w};
    float cv[8] = {c0.x, c0.y, c0.z, c0.w, c1.x, c1.y, c1.z, c1.w};

    float x[8], as = 0.f;
    #pragma unroll
    for (int j = 0; j < 8; ++j) {
        x[j] = (v[j] - mu) * rstd * gv[j] + cv[j];
        as += fabsf(x[j]);
    }
    uint4 pk;
    pk.x = pack_bf16_pair(x[0], x[1]);
    pk.y = pack_bf16_pair(x[2], x[3]);
    pk.z = pack_bf16_pair(x[4], x[5]);
    pk.w = pack_bf16_pair(x[6], x[7]);
    *(uint4*)(xb + (size_t)n * D + lane * 8) = pk;

    #pragma unroll
    for (int o = 1; o <= 32; o <<= 1) as += __shfl_xor(as, o, 64);
    if (lane == 0) {
        int kpm = (as <= 1e-6f);
        kpmf[n] = kpm ? 1.0f : 0.0f;
        wexp[n] = kpm ? 0.0f : __expf(alpha_p[0] * labels[n] + beta_p[0]);
    }
}

// ---------------- W -> bf16 conversion --------------------------------------
__global__ __launch_bounds__(256) void wconv_kernel(
    const float* __restrict__ w, unsigned short* __restrict__ wb)
{
    int i = (blockIdx.x * 256 + threadIdx.x) * 4;
    float4 f = *(const float4*)(w + i);
    ushort2 lo = {f2bf(f.x), f2bf(f.y)};
    ushort2 hi = {f2bf(f.z), f2bf(f.w)};
    *(ushort2*)(wb + i) = lo;
    *(ushort2*)(wb + i + 2) = hi;
}

// ---------------- wfrag fill: V-fragment nt=4 column = w (for l via MFMA) ---
// vfrag chunk layout: chunk = ((bh*32 + t64)*2 + kk)*5 + nt5; 1 KB per chunk,
// lane-major (lane*16B + e*2B). nt5==4: lane lm==0 holds w[key], else 0.
__global__ __launch_bounds__(256) void wfrag_fill(
    const float* __restrict__ wexp, unsigned short* __restrict__ vfrag)
{
    int idx = blockIdx.x * 256 + threadIdx.x;   // 0..131071
    int lane = idx & 63, chunk = idx >> 6;      // chunk = (bh*32+t64)*2+kk
    int kk = chunk & 1, t64 = (chunk >> 1) & 31, bh = chunk >> 6;
    int lm = lane & 15, quad = lane >> 4;
    int b_ = bh >> 3;
    size_t base = (((size_t)chunk * 5 + 4) * 64 + lane) * 8;
    if (lm == 0) {
        int key0 = t64 * 64 + kk * 32 + quad * 8;
        const float* wp = wexp + b_ * T + key0;
        unsigned short vv[8];
        #pragma unroll
        for (int e = 0; e < 8; ++e) vv[e] = f2bf(wp[e]);
        *(uint4*)(vfrag + base) = *(uint4*)vv;
    } else {
        uint4 z = {0u, 0u, 0u, 0u};
        *(uint4*)(vfrag + base) = z;
    }
}

// ---------------- Kernel B: QKV projection -> fragment-order outputs --------
// qfrag: A-frags per 32-query group: (((bh*64+t32)*2+mf)*2+kk)*64 + lane
// kfrag: B-frags, key perm lm*4+nt:   (((bh*32+t64)*2+kk)*4+nt)*64 + lane
// vfrag: B-frags (V' = w*V), nt5 0..3: (((bh*32+t64)*2+kk)*5+nt)*64 + lane
__global__ __launch_bounds__(256) void qkv_mfma(
    const unsigned short* __restrict__ xb, const unsigned short* __restrict__ wb,
    const float* __restrict__ bias, const float* __restrict__ wexp,
    unsigned short* __restrict__ qfrag, unsigned short* __restrict__ kfrag,
    unsigned short* __restrict__ vfrag)
{
    int tid = threadIdx.x;
    int wave = tid >> 6, lane = tid & 63, quad = lane >> 4, lm = lane & 15;
    int wr = wave >> 1, wc = wave & 1;
    int m0 = blockIdx.x * 128 + wr * 64;
    int j0 = blockIdx.y * 128 + wc * 64;

    f32x4 acc[4][4];
    #pragma unroll
    for (int a = 0; a < 4; ++a)
        #pragma unroll
        for (int b = 0; b < 4; ++b) acc[a][b] = (f32x4){0.f,0.f,0.f,0.f};

    for (int kk = 0; kk < D; kk += 32) {
        bf16x8 af[4], bf[4];
        #pragma unroll
        for (int mf = 0; mf < 4; ++mf)
            af[mf] = *(const bf16x8*)(xb + (size_t)(m0 + mf * 16 + lm) * D + kk + quad * 8);
        #pragma unroll
        for (int nt = 0; nt < 4; ++nt)
            bf[nt] = *(const bf16x8*)(wb + (size_t)(j0 + nt * 16 + lm) * D + kk + quad * 8);
        #pragma unroll
        for (int mf = 0; mf < 4; ++mf)
            #pragma unroll
            for (int nt = 0; nt < 4; ++nt)
                acc[mf][nt] = __builtin_amdgcn_mfma_f32_16x16x32_bf16(af[mf], bf[nt], acc[mf][nt], 0, 0, 0);
    }

    int part = j0 >> 9;            // 0=q,1=k,2=v
    int h = (j0 & 511) >> 6;
    float bcol[4];
    #pragma unroll
    for (int nt = 0; nt < 4; ++nt) bcol[nt] = bias[j0 + nt * 16 + lm];

    #pragma unroll
    for (int mf = 0; mf < 4; ++mf) {
        #pragma unroll
        for (int r = 0; r < 4; ++r) {
            int tok = m0 + mf * 16 + quad * 4 + r;
            int b_ = tok >> 11, t = tok & (T - 1);
            int bh = b_ * NH + h;
            float wv = (part == 2) ? wexp[b_ * T + t] : 0.f;
            #pragma unroll
            for (int nt = 0; nt < 4; ++nt) {
                int dh = nt * 16 + lm;
                float val = acc[mf][nt][r] + bcol[nt];
                if (part == 0) {
                    int t32 = t >> 5, mfa = (t >> 4) & 1, lma = t & 15;
                    int kk2 = dh >> 5, quada = (dh >> 3) & 3, e = dh & 7;
                    size_t a = (((((size_t)bh * 64 + t32) * 2 + mfa) * 2 + kk2) * 64
                                + quada * 16 + lma) * 8 + e;
                    qfrag[a] = f2bf(val * QSCALE);
                } else if (part == 1) {
                    int t64 = t >> 6, lma = (t >> 2) & 15, nta = t & 3;
                    int kk2 = dh >> 5, quada = (dh >> 3) & 3, e = dh & 7;
                    size_t a = (((((size_t)bh * 32 + t64) * 2 + kk2) * 4 + nta) * 64
                                + quada * 16 + lma) * 8 + e;
                    kfrag[a] = f2bf(val);
                } else {
                    int t64 = t >> 6, kk2 = (t >> 5) & 1, quada = (t >> 3) & 3, e = t & 7;
                    size_t a = (((((size_t)bh * 32 + t64) * 2 + kk2) * 5 + nt) * 64
                                + quada * 16 + lm) * 8 + e;
                    vfrag[a] = f2bf(val * wv);
                }
            }
        }
    }
}

// ---------------- Kernel C: flash attention, coalesced frag loads -----------
// Block = 128 queries x full T keys of one bh; all loads are contiguous 1-KB
// wave bursts. p = exp2(s); bias/mask folded into V'; l via MFMA w-column.
// Pooling fused (atomicAdd into S).
__global__ __launch_bounds__(256) void attn_mfma(
    const unsigned short* __restrict__ qfrag, const unsigned short* __restrict__ kfrag,
    const unsigned short* __restrict__ vfrag, const float* __restrict__ kpmf,
    float* __restrict__ S)
{
    __shared__ __align__(16) unsigned short Ps[128][72];
    int g = blockIdx.x;
    int bh = g & 31, q0 = (g >> 5) * 128;   // XCD = g%8 = bh%8 -> L2 locality
    int tid = threadIdx.x, wave = tid >> 6, lane = tid & 63;
    int quad = lane >> 4, lm = lane & 15;
    int b_ = bh >> 3, h = bh & 7;

    bf16x8 qf[2][2];
    int t32 = (q0 >> 5) + wave;
    #pragma unroll
    for (int mf = 0; mf < 2; ++mf)
        #pragma unroll
        for (int kk = 0; kk < 2; ++kk)
            qf[mf][kk] = *(const bf16x8*)(qfrag +
                ((((size_t)(bh * 64 + t32) * 2 + mf) * 2 + kk) * 64 + lane) * 8);

    f32x4 accO[2][4], accL[2];
    #pragma unroll
    for (int mf = 0; mf < 2; ++mf) {
        #pragma unroll
        for (int nt = 0; nt < 4; ++nt) accO[mf][nt] = (f32x4){0.f,0.f,0.f,0.f};
        accL[mf] = (f32x4){0.f,0.f,0.f,0.f};
    }

    for (int t64 = 0; t64 < 32; ++t64) {
        bf16x8 kf[4][2], vf[5][2];
        #pragma unroll
        for (int kk = 0; kk < 2; ++kk)
            #pragma unroll
            for (int nt = 0; nt < 4; ++nt)
                kf[nt][kk] = *(const bf16x8*)(kfrag +
                    (((size_t)(bh * 32 + t64) * 2 + kk) * 4 + nt) * 512 + lane * 8);
        #pragma unroll
        for (int kk = 0; kk < 2; ++kk)
            #pragma unroll
            for (int nt = 0; nt < 5; ++nt)
                vf[nt][kk] = *(const bf16x8*)(vfrag +
                    (((size_t)(bh * 32 + t64) * 2 + kk) * 5 + nt) * 512 + lane * 8);

        // S = Q.K^T  (exp2 domain; q pre-scaled; col (lm,nt) = key lm*4+nt)
        f32x4 s[2][4];
        #pragma unroll
        for (int mf = 0; mf < 2; ++mf)
            #pragma unroll
            for (int nt = 0; nt < 4; ++nt) {
                f32x4 t0 = (f32x4){0.f,0.f,0.f,0.f};
                t0 = __builtin_amdgcn_mfma_f32_16x16x32_bf16(qf[mf][0], kf[nt][0], t0, 0, 0, 0);
                t0 = __builtin_amdgcn_mfma_f32_16x16x32_bf16(qf[mf][1], kf[nt][1], t0, 0, 0, 0);
                s[mf][nt] = t0;
            }

        // p = exp2(s); pack 4 consecutive keys -> one b64 LDS write
        #pragma unroll
        for (int mf = 0; mf < 2; ++mf) {
            int rowb = wave * 32 + mf * 16 + quad * 4;
            #pragma unroll
            for (int r = 0; r < 4; ++r) {
                float p0 = __builtin_amdgcn_exp2f(s[mf][0][r]);
                float p1 = __builtin_amdgcn_exp2f(s[mf][1][r]);
                float p2 = __builtin_amdgcn_exp2f(s[mf][2][r]);
                float p3 = __builtin_amdgcn_exp2f(s[mf][3][r]);
                uint2 pw;
                pw.x = pack_bf16_pair(p0, p1);
                pw.y = pack_bf16_pair(p2, p3);
                *(uint2*)&Ps[rowb + r][lm * 4] = pw;
            }
        }

        bf16x8 pf[2][2];
        #pragma unroll
        for (int mf = 0; mf < 2; ++mf)
            #pragma unroll
            for (int kk = 0; kk < 2; ++kk)
                pf[mf][kk] = *(const bf16x8*)&Ps[wave * 32 + mf * 16 + lm][kk * 32 + quad * 8];

        #pragma unroll
        for (int mf = 0; mf < 2; ++mf) {
            #pragma unroll
            for (int nt = 0; nt < 4; ++nt) {
                accO[mf][nt] = __builtin_amdgcn_mfma_f32_16x16x32_bf16(pf[mf][0], vf[nt][0], accO[mf][nt], 0, 0, 0);
                accO[mf][nt] = __builtin_amdgcn_mfma_f32_16x16x32_bf16(pf[mf][1], vf[nt][1], accO[mf][nt], 0, 0, 0);
            }
            accL[mf] = __builtin_amdgcn_mfma_f32_16x16x32_bf16(pf[mf][0], vf[4][0], accL[mf], 0, 0, 0);
            accL[mf] = __builtin_amdgcn_mfma_f32_16x16x32_bf16(pf[mf][1], vf[4][1], accL[mf], 0, 0, 0);
        }
    }

    // fused masked pooling: l lives in col 0 (lane lm==0 of each quad group)
    float pooled[4] = {0.f, 0.f, 0.f, 0.f};
    #pragma unroll
    for (int mf = 0; mf < 2; ++mf)
        #pragma unroll
        for (int r = 0; r < 4; ++r) {
            int row = q0 + wave * 32 + mf * 16 + quad * 4 + r;
            float l = __shfl(accL[mf][r], lane & 48, 64);
            float w = (1.0f - kpmf[b_ * T + row]) / l;
            #pragma unroll
            for (int nt = 0; nt < 4; ++nt) pooled[nt] += accO[mf][nt][r] * w;
        }
    #pragma unroll
    for (int nt = 0; nt < 4; ++nt) {
        pooled[nt] += __shfl_xor(pooled[nt], 16, 64);
        pooled[nt] += __shfl_xor(pooled[nt], 32, 64);
    }
    if (quad == 0) {
        #pragma unroll
        for (int nt = 0; nt < 4; ++nt)
            atomicAdd(&S[b_ * D + h * DH + nt * 16 + lm], pooled[nt]);
    }
}

// ---------------- Kernel E: out-projection of pooled vector + bias ----------
__global__ __launch_bounds__(256) void out_kernel(
    const float* __restrict__ S, const float* __restrict__ kpmf,
    const float* __restrict__ Wo, const float* __restrict__ bo,
    float* __restrict__ out)
{
    __shared__ float Sl[512];
    __shared__ float cs[4];
    __shared__ float pr[4][64];
    int b_ = blockIdx.x >> 3;
    int cg = blockIdx.x & 7;
    int tid = threadIdx.x;
    int col = tid & 63, kq = tid >> 6;
    Sl[tid] = S[b_ * D + tid];
    Sl[tid + 256] = S[b_ * D + tid + 256];
    const float* kp = kpmf + b_ * T;
    float c = 0.f;
    for (int t = tid; t < T; t += 256) c += kp[t];
    #pragma unroll
    for (int o = 32; o; o >>= 1) c += __shfl_xor(c, o, 64);
    if ((tid & 63) == 0) cs[tid >> 6] = c;
    __syncthreads();
    float masked = cs[0] + cs[1] + cs[2] + cs[3];
    float cnt = (float)T - masked;
    float inv = 1.0f / fmaxf(cnt, 1.0f);

    int d = cg * 64 + col;
    const float4* wr4 = (const float4*)(Wo + (size_t)d * D + kq * 128);
    float dot = 0.f;
    #pragma unroll 8
    for (int i = 0; i < 32; ++i) {
        float4 w4 = wr4[i];
        int kbase = kq * 128 + i * 4;
        dot += Sl[kbase + 0] * w4.x + Sl[kbase + 1] * w4.y +
               Sl[kbase + 2] * w4.z + Sl[kbase + 3] * w4.w;
    }
    pr[kq][col] = dot;
    __syncthreads();
    if (kq == 0) {
        float tot = pr[0][col] + pr[1][col] + pr[2][col] + pr[3][col];
        out[b_ * D + d] = (tot + bo[d] * cnt) * inv;
    }
}

extern "C" void kernel_launch(void* const* d_in, const int* in_sizes, int n_in,
                              void* d_out, int out_size, void* d_ws, size_t ws_size,
                              hipStream_t stream) {
    const float* embs   = (const float*)d_in[0];
    const float* labels = (const float*)d_in[1];
    const float* ln_g   = (const float*)d_in[2];
    const float* ln_b   = (const float*)d_in[3];
    const float* ipw    = (const float*)d_in[4];
    const float* ipb    = (const float*)d_in[5];
    const float* ow     = (const float*)d_in[6];
    const float* obb    = (const float*)d_in[7];
    const float* alpha  = (const float*)d_in[8];
    const float* beta   = (const float*)d_in[9];
    float* out = (float*)d_out;

    unsigned short* xb    = (unsigned short*)d_ws;           // 8192*512
    unsigned short* wb    = xb + (size_t)NTOK * D;           // 1536*512
    unsigned short* qfrag = wb + (size_t)3 * D * D;          // 32*2048*64
    unsigned short* kfrag = qfrag + (size_t)NTOK * D;        // 32*2048*64
    unsigned short* vfrag = kfrag + (size_t)NTOK * D;        // 32*32*2*5*512
    float* wexp = (float*)(vfrag + (size_t)32 * 32 * 2 * 5 * 512);  // 8192
    float* kpmf = wexp + NTOK;                               // 8192
    float* S    = kpmf + NTOK;                               // 2048

    hipMemsetAsync(S, 0, (size_t)NB * D * sizeof(float), stream);
    ln_kernel<<<NTOK / 4, 256, 0, stream>>>(embs, labels, ln_g, ln_b, alpha, beta,
                                            xb, wexp, kpmf);
    wconv_kernel<<<(3 * D * D) / 1024, 256, 0, stream>>>(ipw, wb);
    wfrag_fill<<<512, 256, 0, stream>>>(wexp, vfrag);
    dim3 gq(NTOK / 128, (3 * D) / 128);
    qkv_mfma<<<gq, 256, 0, stream>>>(xb, wb, ipb, wexp, qfrag, kfrag, vfrag);
    attn_mfma<<<32 * (T / 128), 256, 0, stream>>>(qfrag, kfrag, vfrag, kpmf, S);
    out_kernel<<<NB * 8, 256, 0, stream>>>(S, kpmf, ow, obb, out);
}

// Round 8
// 177.566 us; speedup vs baseline: 1.8435x; 1.1863x over previous
//
#include <hip/hip_runtime.h>
#include <math.h>

#define T 2048
#define D 512
#define NH 8
#define DH 64
#define NB 4
#define NTOK (NB * T)   // 8192
#define LOG2E 1.44269504f
#define QSCALE (0.125f * LOG2E)

using bf16x8 = __attribute__((ext_vector_type(8))) short;
using f32x4  = __attribute__((ext_vector_type(4))) float;

static __device__ __forceinline__ unsigned short f2bf(float f) {
    union { float f; unsigned u; } v; v.f = f;
    unsigned r = v.u + 0x7fffu + ((v.u >> 16) & 1u);   // RNE
    return (unsigned short)(r >> 16);
}
#if __has_builtin(__builtin_amdgcn_cvt_pk_bf16_f32)
static __device__ __forceinline__ unsigned pack_bf16_pair(float a, float b) {
    auto r = __builtin_amdgcn_cvt_pk_bf16_f32(a, b);
    union { decltype(r) v; unsigned u; } c; c.v = r;
    return c.u;
}
#else
static __device__ __forceinline__ unsigned pack_bf16_pair(float a, float b) {
    union { float f; unsigned u; } ua, ub; ua.f = a; ub.f = b;
    unsigned ra = ua.u + 0x7fffu + ((ua.u >> 16) & 1u);
    unsigned rb = ub.u + 0x7fffu + ((ub.u >> 16) & 1u);
    return __builtin_amdgcn_perm(rb, ra, 0x07060302);
}
#endif

// Fragment layouts (lane = quad*16+lm, 8 bf16 per lane, 1 KB per chunk):
// xfrag  A-frag: chunk = t16*16 + kc           elem = x[t16*16+lm][kc*32+quad*8+e]
// wbfrag B-frag: chunk = j16*16 + kc           elem = W[j16*16+lm][kc*32+quad*8+e]
// qfrag  A-frag: chunk = (bh*128+t16)*2+kk     elem = q[t16*16+lm][kk*32+quad*8+e]
// kfrag  B-frag: chunk = ((bh*32+t64)*2+kk)*4+nt  elem = k[key=t64*64+lm*4+nt][kk*32+quad*8+e]
// vfrag  B-frag: chunk = ((bh*32+t64)*2+kk)*5+nt  elem = v'[dh=nt*16+lm][key=t64*64+kk*32+quad*8+e]
//        (nt=4 column of vfrag = w-vector for l-via-MFMA, filled by wfrag_fill)

// ---------------- Kernel A: LayerNorm -> A-fragment-order x -----------------
__global__ __launch_bounds__(256) void ln_kernel(
    const float* __restrict__ embs, const float* __restrict__ labels,
    const float* __restrict__ g, const float* __restrict__ bb,
    const float* __restrict__ alpha_p, const float* __restrict__ beta_p,
    unsigned short* __restrict__ xfrag, float* __restrict__ wexp,
    float* __restrict__ kpmf)
{
    __shared__ __align__(16) unsigned short Xs[16][520];
    int tid = threadIdx.x, wave = tid >> 6, lane = tid & 63;
    int quad = lane >> 4, lm = lane & 15;
    int t16 = blockIdx.x;

    float4 g0 = *(const float4*)(g + lane * 8), g1 = *(const float4*)(g + lane * 8 + 4);
    float4 c0 = *(const float4*)(bb + lane * 8), c1 = *(const float4*)(bb + lane * 8 + 4);
    float gv[8] = {g0.x, g0.y, g0.z, g0.w, g1.x, g1.y, g1.z, g1.w};
    float cv[8] = {c0.x, c0.y, c0.z, c0.w, c1.x, c1.y, c1.z, c1.w};

    for (int tt = 0; tt < 4; ++tt) {
        int n = t16 * 16 + wave * 4 + tt;
        const float* e = embs + (size_t)n * D + lane * 8;
        float4 a4 = *(const float4*)e, b4 = *(const float4*)(e + 4);
        float v[8] = {a4.x, a4.y, a4.z, a4.w, b4.x, b4.y, b4.z, b4.w};

        float s = 0.f, ss = 0.f;
        #pragma unroll
        for (int j = 0; j < 8; ++j) { s += v[j]; ss += v[j] * v[j]; }
        #pragma unroll
        for (int o = 1; o <= 32; o <<= 1) {
            s += __shfl_xor(s, o, 64);
            ss += __shfl_xor(ss, o, 64);
        }
        float mu = s * (1.0f / D);
        float var = ss * (1.0f / D) - mu * mu;
        float rstd = rsqrtf(var + 1e-5f);

        float x[8], as = 0.f;
        #pragma unroll
        for (int j = 0; j < 8; ++j) {
            x[j] = (v[j] - mu) * rstd * gv[j] + cv[j];
            as += fabsf(x[j]);
        }
        uint4 pk;
        pk.x = pack_bf16_pair(x[0], x[1]);
        pk.y = pack_bf16_pair(x[2], x[3]);
        pk.z = pack_bf16_pair(x[4], x[5]);
        pk.w = pack_bf16_pair(x[6], x[7]);
        *(uint4*)&Xs[wave * 4 + tt][lane * 8] = pk;

        #pragma unroll
        for (int o = 1; o <= 32; o <<= 1) as += __shfl_xor(as, o, 64);
        if (lane == 0) {
            int kpm = (as <= 1e-6f);
            kpmf[n] = kpm ? 1.0f : 0.0f;
            wexp[n] = kpm ? 0.0f : __expf(alpha_p[0] * labels[n] + beta_p[0]);
        }
    }
    __syncthreads();
    #pragma unroll
    for (int i = 0; i < 4; ++i) {
        int kc = wave * 4 + i;
        bf16x8 fr = *(const bf16x8*)&Xs[lm][kc * 32 + quad * 8];
        *(bf16x8*)(xfrag + ((size_t)(t16 * 16 + kc) * 64 + lane) * 8) = fr;
    }
}

// ---------------- W -> bf16 B-fragment order --------------------------------
__global__ __launch_bounds__(256) void wconv_kernel(
    const float* __restrict__ w, unsigned short* __restrict__ wbfrag)
{
    __shared__ __align__(16) unsigned short Ws[16][520];
    int tid = threadIdx.x, wave = tid >> 6, lane = tid & 63;
    int quad = lane >> 4, lm = lane & 15;
    int j16 = blockIdx.x;

    for (int tt = 0; tt < 4; ++tt) {
        int j = j16 * 16 + wave * 4 + tt;
        const float* wp = w + (size_t)j * D + lane * 8;
        float4 a4 = *(const float4*)wp, b4 = *(const float4*)(wp + 4);
        uint4 pk;
        pk.x = pack_bf16_pair(a4.x, a4.y);
        pk.y = pack_bf16_pair(a4.z, a4.w);
        pk.z = pack_bf16_pair(b4.x, b4.y);
        pk.w = pack_bf16_pair(b4.z, b4.w);
        *(uint4*)&Ws[wave * 4 + tt][lane * 8] = pk;
    }
    __syncthreads();
    #pragma unroll
    for (int i = 0; i < 4; ++i) {
        int kc = wave * 4 + i;
        bf16x8 fr = *(const bf16x8*)&Ws[lm][kc * 32 + quad * 8];
        *(bf16x8*)(wbfrag + ((size_t)(j16 * 16 + kc) * 64 + lane) * 8) = fr;
    }
}

// ---------------- wfrag fill: V-fragment nt=4 column = w --------------------
__global__ __launch_bounds__(256) void wfrag_fill(
    const float* __restrict__ wexp, unsigned short* __restrict__ vfrag)
{
    int idx = blockIdx.x * 256 + threadIdx.x;   // 0..131071
    int lane = idx & 63, chunk = idx >> 6;      // chunk = (bh*32+t64)*2+kk
    int kk = chunk & 1, t64 = (chunk >> 1) & 31, bh = chunk >> 6;
    int lm = lane & 15, quad = lane >> 4;
    int b_ = bh >> 3;
    size_t base = (((size_t)chunk * 5 + 4) * 64 + lane) * 8;
    if (lm == 0) {
        int key0 = t64 * 64 + kk * 32 + quad * 8;
        const float* wp = wexp + b_ * T + key0;
        unsigned short vv[8];
        #pragma unroll
        for (int e = 0; e < 8; ++e) vv[e] = f2bf(wp[e]);
        *(uint4*)(vfrag + base) = *(uint4*)vv;
    } else {
        uint4 z = {0u, 0u, 0u, 0u};
        *(uint4*)(vfrag + base) = z;
    }
}

// ---------------- Kernel B: QKV projection, all-coalesced -------------------
__global__ __launch_bounds__(256) void qkv_mfma(
    const unsigned short* __restrict__ xfrag, const unsigned short* __restrict__ wbfrag,
    const float* __restrict__ bias, const float* __restrict__ wexp,
    unsigned short* __restrict__ qfrag, unsigned short* __restrict__ kfrag,
    unsigned short* __restrict__ vfrag)
{
    __shared__ __align__(16) unsigned short Ls[4][64][72];
    int tid = threadIdx.x;
    int wave = tid >> 6, lane = tid & 63, quad = lane >> 4, lm = lane & 15;
    int wr = wave >> 1, wc = wave & 1;
    int m0 = blockIdx.x * 128 + wr * 64;
    int j0 = blockIdx.y * 128 + wc * 64;
    int mt16 = m0 >> 4, jt16 = j0 >> 4;

    f32x4 acc[4][4];
    #pragma unroll
    for (int a = 0; a < 4; ++a)
        #pragma unroll
        for (int b = 0; b < 4; ++b) acc[a][b] = (f32x4){0.f,0.f,0.f,0.f};

    for (int kc = 0; kc < 16; ++kc) {
        bf16x8 af[4], bf[4];
        #pragma unroll
        for (int mf = 0; mf < 4; ++mf)
            af[mf] = *(const bf16x8*)(xfrag + ((size_t)((mt16 + mf) * 16 + kc) * 64 + lane) * 8);
        #pragma unroll
        for (int nt = 0; nt < 4; ++nt)
            bf[nt] = *(const bf16x8*)(wbfrag + ((size_t)((jt16 + nt) * 16 + kc) * 64 + lane) * 8);
        #pragma unroll
        for (int mf = 0; mf < 4; ++mf)
            #pragma unroll
            for (int nt = 0; nt < 4; ++nt)
                acc[mf][nt] = __builtin_amdgcn_mfma_f32_16x16x32_bf16(af[mf], bf[nt], acc[mf][nt], 0, 0, 0);
    }

    int part = j0 >> 9;            // 0=q,1=k,2=v
    int h = (j0 & 511) >> 6;
    int b_ = m0 >> 11, tloc = m0 & (T - 1);
    int bh = b_ * NH + h;
    float bcol[4];
    #pragma unroll
    for (int nt = 0; nt < 4; ++nt) bcol[nt] = bias[j0 + nt * 16 + lm];

    if (part == 2) {
        // LDS [dh][key]; C-layout r-runs are contiguous keys -> b64 writes
        float wv[4][4];
        #pragma unroll
        for (int mf = 0; mf < 4; ++mf)
            #pragma unroll
            for (int r = 0; r < 4; ++r)
                wv[mf][r] = wexp[b_ * T + tloc + mf * 16 + quad * 4 + r];
        #pragma unroll
        for (int mf = 0; mf < 4; ++mf)
            #pragma unroll
            for (int nt = 0; nt < 4; ++nt) {
                uint2 pw;
                pw.x = pack_bf16_pair((acc[mf][nt][0] + bcol[nt]) * wv[mf][0],
                                      (acc[mf][nt][1] + bcol[nt]) * wv[mf][1]);
                pw.y = pack_bf16_pair((acc[mf][nt][2] + bcol[nt]) * wv[mf][2],
                                      (acc[mf][nt][3] + bcol[nt]) * wv[mf][3]);
                *(uint2*)&Ls[wave][nt * 16 + lm][mf * 16 + quad * 4] = pw;
            }
        #pragma unroll
        for (int nt = 0; nt < 4; ++nt)
            #pragma unroll
            for (int kk = 0; kk < 2; ++kk) {
                bf16x8 fr = *(const bf16x8*)&Ls[wave][nt * 16 + lm][kk * 32 + quad * 8];
                size_t chunk = (((size_t)bh * 32 + (tloc >> 6)) * 2 + kk) * 5 + nt;
                *(bf16x8*)(vfrag + chunk * 512 + lane * 8) = fr;
            }
    } else {
        // LDS [token][dh]; scalar b16 writes (one-time), b128 frag reads
        float scale = (part == 0) ? QSCALE : 1.0f;
        #pragma unroll
        for (int mf = 0; mf < 4; ++mf)
            #pragma unroll
            for (int nt = 0; nt < 4; ++nt)
                #pragma unroll
                for (int r = 0; r < 4; ++r)
                    Ls[wave][mf * 16 + quad * 4 + r][nt * 16 + lm] =
                        f2bf((acc[mf][nt][r] + bcol[nt]) * scale);
        if (part == 0) {
            #pragma unroll
            for (int mf = 0; mf < 4; ++mf)
                #pragma unroll
                for (int kk = 0; kk < 2; ++kk) {
                    bf16x8 fr = *(const bf16x8*)&Ls[wave][mf * 16 + lm][kk * 32 + quad * 8];
                    size_t chunk = ((size_t)bh * 128 + (tloc >> 4) + mf) * 2 + kk;
                    *(bf16x8*)(qfrag + chunk * 512 + lane * 8) = fr;
                }
        } else {
            #pragma unroll
            for (int nta = 0; nta < 4; ++nta)
                #pragma unroll
                for (int kk = 0; kk < 2; ++kk) {
                    bf16x8 fr = *(const bf16x8*)&Ls[wave][lm * 4 + nta][kk * 32 + quad * 8];
                    size_t chunk = (((size_t)bh * 32 + (tloc >> 6)) * 2 + kk) * 4 + nta;
                    *(bf16x8*)(kfrag + chunk * 512 + lane * 8) = fr;
                }
        }
    }
}

// ---------------- Kernel C: flash attention, coalesced frag loads -----------
__global__ __launch_bounds__(256) void attn_mfma(
    const unsigned short* __restrict__ qfrag, const unsigned short* __restrict__ kfrag,
    const unsigned short* __restrict__ vfrag, const float* __restrict__ kpmf,
    float* __restrict__ S)
{
    __shared__ __align__(16) unsigned short Ps[128][72];
    int g = blockIdx.x;
    int bh = g & 31, q0 = (g >> 5) * 128;   // XCD = g%8 = bh%8 -> L2 locality
    int tid = threadIdx.x, wave = tid >> 6, lane = tid & 63;
    int quad = lane >> 4, lm = lane & 15;
    int b_ = bh >> 3, h = bh & 7;

    bf16x8 qf[2][2];
    int t32 = (q0 >> 5) + wave;
    #pragma unroll
    for (int mf = 0; mf < 2; ++mf)
        #pragma unroll
        for (int kk = 0; kk < 2; ++kk)
            qf[mf][kk] = *(const bf16x8*)(qfrag +
                ((((size_t)(bh * 64 + t32) * 2 + mf) * 2 + kk) * 64 + lane) * 8);

    f32x4 accO[2][4], accL[2];
    #pragma unroll
    for (int mf = 0; mf < 2; ++mf) {
        #pragma unroll
        for (int nt = 0; nt < 4; ++nt) accO[mf][nt] = (f32x4){0.f,0.f,0.f,0.f};
        accL[mf] = (f32x4){0.f,0.f,0.f,0.f};
    }

    for (int t64 = 0; t64 < 32; ++t64) {
        bf16x8 kf[4][2], vf[5][2];
        #pragma unroll
        for (int kk = 0; kk < 2; ++kk)
            #pragma unroll
            for (int nt = 0; nt < 4; ++nt)
                kf[nt][kk] = *(const bf16x8*)(kfrag +
                    (((size_t)(bh * 32 + t64) * 2 + kk) * 4 + nt) * 512 + lane * 8);
        #pragma unroll
        for (int kk = 0; kk < 2; ++kk)
            #pragma unroll
            for (int nt = 0; nt < 5; ++nt)
                vf[nt][kk] = *(const bf16x8*)(vfrag +
                    (((size_t)(bh * 32 + t64) * 2 + kk) * 5 + nt) * 512 + lane * 8);

        f32x4 s[2][4];
        #pragma unroll
        for (int mf = 0; mf < 2; ++mf)
            #pragma unroll
            for (int nt = 0; nt < 4; ++nt) {
                f32x4 t0 = (f32x4){0.f,0.f,0.f,0.f};
                t0 = __builtin_amdgcn_mfma_f32_16x16x32_bf16(qf[mf][0], kf[nt][0], t0, 0, 0, 0);
                t0 = __builtin_amdgcn_mfma_f32_16x16x32_bf16(qf[mf][1], kf[nt][1], t0, 0, 0, 0);
                s[mf][nt] = t0;
            }

        #pragma unroll
        for (int mf = 0; mf < 2; ++mf) {
            int rowb = wave * 32 + mf * 16 + quad * 4;
            #pragma unroll
            for (int r = 0; r < 4; ++r) {
                float p0 = __builtin_amdgcn_exp2f(s[mf][0][r]);
                float p1 = __builtin_amdgcn_exp2f(s[mf][1][r]);
                float p2 = __builtin_amdgcn_exp2f(s[mf][2][r]);
                float p3 = __builtin_amdgcn_exp2f(s[mf][3][r]);
                uint2 pw;
                pw.x = pack_bf16_pair(p0, p1);
                pw.y = pack_bf16_pair(p2, p3);
                *(uint2*)&Ps[rowb + r][lm * 4] = pw;
            }
        }

        bf16x8 pf[2][2];
        #pragma unroll
        for (int mf = 0; mf < 2; ++mf)
            #pragma unroll
            for (int kk = 0; kk < 2; ++kk)
                pf[mf][kk] = *(const bf16x8*)&Ps[wave * 32 + mf * 16 + lm][kk * 32 + quad * 8];

        #pragma unroll
        for (int mf = 0; mf < 2; ++mf) {
            #pragma unroll
            for (int nt = 0; nt < 4; ++nt) {
                accO[mf][nt] = __builtin_amdgcn_mfma_f32_16x16x32_bf16(pf[mf][0], vf[nt][0], accO[mf][nt], 0, 0, 0);
                accO[mf][nt] = __builtin_amdgcn_mfma_f32_16x16x32_bf16(pf[mf][1], vf[nt][1], accO[mf][nt], 0, 0, 0);
            }
            accL[mf] = __builtin_amdgcn_mfma_f32_16x16x32_bf16(pf[mf][0], vf[4][0], accL[mf], 0, 0, 0);
            accL[mf] = __builtin_amdgcn_mfma_f32_16x16x32_bf16(pf[mf][1], vf[4][1], accL[mf], 0, 0, 0);
        }
    }

    float pooled[4] = {0.f, 0.f, 0.f, 0.f};
    #pragma unroll
    for (int mf = 0; mf < 2; ++mf)
        #pragma unroll
        for (int r = 0; r < 4; ++r) {
            int row = q0 + wave * 32 + mf * 16 + quad * 4 + r;
            float l = __shfl(accL[mf][r], lane & 48, 64);
            float w = (1.0f - kpmf[b_ * T + row]) / l;
            #pragma unroll
            for (int nt = 0; nt < 4; ++nt) pooled[nt] += accO[mf][nt][r] * w;
        }
    #pragma unroll
    for (int nt = 0; nt < 4; ++nt) {
        pooled[nt] += __shfl_xor(pooled[nt], 16, 64);
        pooled[nt] += __shfl_xor(pooled[nt], 32, 64);
    }
    if (quad == 0) {
        #pragma unroll
        for (int nt = 0; nt < 4; ++nt)
            atomicAdd(&S[b_ * D + h * DH + nt * 16 + lm], pooled[nt]);
    }
}

// ---------------- Kernel E: out-projection of pooled vector + bias ----------
__global__ __launch_bounds__(256) void out_kernel(
    const float* __restrict__ S, const float* __restrict__ kpmf,
    const float* __restrict__ Wo, const float* __restrict__ bo,
    float* __restrict__ out)
{
    __shared__ float Sl[512];
    __shared__ float cs[4];
    __shared__ float pr[4][64];
    int b_ = blockIdx.x >> 3;
    int cg = blockIdx.x & 7;
    int tid = threadIdx.x;
    int col = tid & 63, kq = tid >> 6;
    Sl[tid] = S[b_ * D + tid];
    Sl[tid + 256] = S[b_ * D + tid + 256];
    const float* kp = kpmf + b_ * T;
    float c = 0.f;
    for (int t = tid; t < T; t += 256) c += kp[t];
    #pragma unroll
    for (int o = 32; o; o >>= 1) c += __shfl_xor(c, o, 64);
    if ((tid & 63) == 0) cs[tid >> 6] = c;
    __syncthreads();
    float masked = cs[0] + cs[1] + cs[2] + cs[3];
    float cnt = (float)T - masked;
    float inv = 1.0f / fmaxf(cnt, 1.0f);

    int d = cg * 64 + col;
    const float4* wr4 = (const float4*)(Wo + (size_t)d * D + kq * 128);
    float dot = 0.f;
    #pragma unroll 8
    for (int i = 0; i < 32; ++i) {
        float4 w4 = wr4[i];
        int kbase = kq * 128 + i * 4;
        dot += Sl[kbase + 0] * w4.x + Sl[kbase + 1] * w4.y +
               Sl[kbase + 2] * w4.z + Sl[kbase + 3] * w4.w;
    }
    pr[kq][col] = dot;
    __syncthreads();
    if (kq == 0) {
        float tot = pr[0][col] + pr[1][col] + pr[2][col] + pr[3][col];
        out[b_ * D + d] = (tot + bo[d] * cnt) * inv;
    }
}

extern "C" void kernel_launch(void* const* d_in, const int* in_sizes, int n_in,
                              void* d_out, int out_size, void* d_ws, size_t ws_size,
                              hipStream_t stream) {
    const float* embs   = (const float*)d_in[0];
    const float* labels = (const float*)d_in[1];
    const float* ln_g   = (const float*)d_in[2];
    const float* ln_b   = (const float*)d_in[3];
    const float* ipw    = (const float*)d_in[4];
    const float* ipb    = (const float*)d_in[5];
    const float* ow     = (const float*)d_in[6];
    const float* obb    = (const float*)d_in[7];
    const float* alpha  = (const float*)d_in[8];
    const float* beta   = (const float*)d_in[9];
    float* out = (float*)d_out;

    unsigned short* xfrag  = (unsigned short*)d_ws;          // 8192*512
    unsigned short* wbfrag = xfrag + (size_t)NTOK * D;       // 1536*512
    unsigned short* qfrag  = wbfrag + (size_t)3 * D * D;     // 8192*512
    unsigned short* kfrag  = qfrag + (size_t)NTOK * D;       // 8192*512
    unsigned short* vfrag  = kfrag + (size_t)NTOK * D;       // 32*32*2*5*512
    float* wexp = (float*)(vfrag + (size_t)32 * 32 * 2 * 5 * 512);  // 8192
    float* kpmf = wexp + NTOK;                               // 8192
    float* S    = kpmf + NTOK;                               // 2048

    hipMemsetAsync(S, 0, (size_t)NB * D * sizeof(float), stream);
    ln_kernel<<<NTOK / 16, 256, 0, stream>>>(embs, labels, ln_g, ln_b, alpha, beta,
                                             xfrag, wexp, kpmf);
    wconv_kernel<<<(3 * D) / 16, 256, 0, stream>>>(ipw, wbfrag);
    wfrag_fill<<<512, 256, 0, stream>>>(wexp, vfrag);
    dim3 gq(NTOK / 128, (3 * D) / 128);
    qkv_mfma<<<gq, 256, 0, stream>>>(xfrag, wbfrag, ipb, wexp, qfrag, kfrag, vfrag);
    attn_mfma<<<32 * (T / 128), 256, 0, stream>>>(qfrag, kfrag, vfrag, kpmf, S);
    out_kernel<<<NB * 8, 256, 0, stream>>>(S, kpmf, ow, obb, out);
}

// Round 10
// 174.759 us; speedup vs baseline: 1.8732x; 1.0161x over previous
//
#include <hip/hip_runtime.h>
#include <math.h>

#define T 2048
#define D 512
#define NH 8
#define DH 64
#define NB 4
#define NTOK (NB * T)   // 8192
#define LOG2E 1.44269504f
#define QSCALE (0.125f * LOG2E)

using bf16x8 = __attribute__((ext_vector_type(8))) short;
using f32x4  = __attribute__((ext_vector_type(4))) float;

static __device__ __forceinline__ unsigned short f2bf(float f) {
    union { float f; unsigned u; } v; v.f = f;
    unsigned r = v.u + 0x7fffu + ((v.u >> 16) & 1u);   // RNE
    return (unsigned short)(r >> 16);
}
#if __has_builtin(__builtin_amdgcn_cvt_pk_bf16_f32)
static __device__ __forceinline__ unsigned pack_bf16_pair(float a, float b) {
    auto r = __builtin_amdgcn_cvt_pk_bf16_f32(a, b);
    union { decltype(r) v; unsigned u; } c; c.v = r;
    return c.u;
}
#else
static __device__ __forceinline__ unsigned pack_bf16_pair(float a, float b) {
    union { float f; unsigned u; } ua, ub; ua.f = a; ub.f = b;
    unsigned ra = ua.u + 0x7fffu + ((ua.u >> 16) & 1u);
    unsigned rb = ub.u + 0x7fffu + ((ub.u >> 16) & 1u);
    return __builtin_amdgcn_perm(rb, ra, 0x07060302);
}
#endif

// Fragment layouts (lane = quad*16+lm, 8 bf16 per lane, 1 KB per chunk):
// xfrag  A-frag: chunk = t16*16 + kc           elem = x[t16*16+lm][kc*32+quad*8+e]
// wbfrag B-frag: chunk = j16*16 + kc           elem = W[j16*16+lm][kc*32+quad*8+e]
// qfrag  A-frag: chunk = (bh*128+t16)*2+kk     elem = q[t16*16+lm][kk*32+quad*8+e]
// kfrag  B-frag: chunk = ((bh*32+t64)*2+kk)*4+nt  elem = k[key=t64*64+lm*4+nt][kk*32+quad*8+e]
// vfrag  B-frag: chunk = ((bh*32+t64)*2+kk)*4+nt  elem = v[dh=nt*16+lm][key=t64*64+kk*32+quad*8+e]

// ---------------- Kernel A: LayerNorm -> A-fragment-order x -----------------
// wscaled[n] = (alpha*label+beta)*log2e, or -3e38 if masked (exp2 -> 0).
__global__ __launch_bounds__(256) void ln_kernel(
    const float* __restrict__ embs, const float* __restrict__ labels,
    const float* __restrict__ g, const float* __restrict__ bb,
    const float* __restrict__ alpha_p, const float* __restrict__ beta_p,
    unsigned short* __restrict__ xfrag, float* __restrict__ wscaled,
    float* __restrict__ kpmf)
{
    __shared__ __align__(16) unsigned short Xs[16][520];
    int tid = threadIdx.x, wave = tid >> 6, lane = tid & 63;
    int quad = lane >> 4, lm = lane & 15;
    int t16 = blockIdx.x;

    float4 g0 = *(const float4*)(g + lane * 8), g1 = *(const float4*)(g + lane * 8 + 4);
    float4 c0 = *(const float4*)(bb + lane * 8), c1 = *(const float4*)(bb + lane * 8 + 4);
    float gv[8] = {g0.x, g0.y, g0.z, g0.w, g1.x, g1.y, g1.z, g1.w};
    float cv[8] = {c0.x, c0.y, c0.z, c0.w, c1.x, c1.y, c1.z, c1.w};

    for (int tt = 0; tt < 4; ++tt) {
        int n = t16 * 16 + wave * 4 + tt;
        const float* e = embs + (size_t)n * D + lane * 8;
        float4 a4 = *(const float4*)e, b4 = *(const float4*)(e + 4);
        float v[8] = {a4.x, a4.y, a4.z, a4.w, b4.x, b4.y, b4.z, b4.w};

        float s = 0.f, ss = 0.f;
        #pragma unroll
        for (int j = 0; j < 8; ++j) { s += v[j]; ss += v[j] * v[j]; }
        #pragma unroll
        for (int o = 1; o <= 32; o <<= 1) {
            s += __shfl_xor(s, o, 64);
            ss += __shfl_xor(ss, o, 64);
        }
        float mu = s * (1.0f / D);
        float var = ss * (1.0f / D) - mu * mu;
        float rstd = rsqrtf(var + 1e-5f);

        float x[8], as = 0.f;
        #pragma unroll
        for (int j = 0; j < 8; ++j) {
            x[j] = (v[j] - mu) * rstd * gv[j] + cv[j];
            as += fabsf(x[j]);
        }
        uint4 pk;
        pk.x = pack_bf16_pair(x[0], x[1]);
        pk.y = pack_bf16_pair(x[2], x[3]);
        pk.z = pack_bf16_pair(x[4], x[5]);
        pk.w = pack_bf16_pair(x[6], x[7]);
        *(uint4*)&Xs[wave * 4 + tt][lane * 8] = pk;

        #pragma unroll
        for (int o = 1; o <= 32; o <<= 1) as += __shfl_xor(as, o, 64);
        if (lane == 0) {
            int kpm = (as <= 1e-6f);
            kpmf[n] = kpm ? 1.0f : 0.0f;
            wscaled[n] = kpm ? -3.0e38f
                             : (alpha_p[0] * labels[n] + beta_p[0]) * LOG2E;
        }
    }
    __syncthreads();
    #pragma unroll
    for (int i = 0; i < 4; ++i) {
        int kc = wave * 4 + i;
        bf16x8 fr = *(const bf16x8*)&Xs[lm][kc * 32 + quad * 8];
        *(bf16x8*)(xfrag + ((size_t)(t16 * 16 + kc) * 64 + lane) * 8) = fr;
    }
}

// ---------------- W -> bf16 B-fragment order --------------------------------
__global__ __launch_bounds__(256) void wconv_kernel(
    const float* __restrict__ w, unsigned short* __restrict__ wbfrag)
{
    __shared__ __align__(16) unsigned short Ws[16][520];
    int tid = threadIdx.x, wave = tid >> 6, lane = tid & 63;
    int quad = lane >> 4, lm = lane & 15;
    int j16 = blockIdx.x;

    for (int tt = 0; tt < 4; ++tt) {
        int j = j16 * 16 + wave * 4 + tt;
        const float* wp = w + (size_t)j * D + lane * 8;
        float4 a4 = *(const float4*)wp, b4 = *(const float4*)(wp + 4);
        uint4 pk;
        pk.x = pack_bf16_pair(a4.x, a4.y);
        pk.y = pack_bf16_pair(a4.z, a4.w);
        pk.z = pack_bf16_pair(b4.x, b4.y);
        pk.w = pack_bf16_pair(b4.z, b4.w);
        *(uint4*)&Ws[wave * 4 + tt][lane * 8] = pk;
    }
    __syncthreads();
    #pragma unroll
    for (int i = 0; i < 4; ++i) {
        int kc = wave * 4 + i;
        bf16x8 fr = *(const bf16x8*)&Ws[lm][kc * 32 + quad * 8];
        *(bf16x8*)(wbfrag + ((size_t)(j16 * 16 + kc) * 64 + lane) * 8) = fr;
    }
}

// ---------------- Kernel B: QKV projection, all-coalesced, pipelined --------
__global__ __launch_bounds__(256) void qkv_mfma(
    const unsigned short* __restrict__ xfrag, const unsigned short* __restrict__ wbfrag,
    const float* __restrict__ bias, unsigned short* __restrict__ qfrag,
    unsigned short* __restrict__ kfrag, unsigned short* __restrict__ vfrag)
{
    __shared__ __align__(16) unsigned short Ls[4][64][72];
    int tid = threadIdx.x;
    int wave = tid >> 6, lane = tid & 63, quad = lane >> 4, lm = lane & 15;
    int wr = wave >> 1, wc = wave & 1;
    int m0 = blockIdx.x * 128 + wr * 64;
    int j0 = blockIdx.y * 128 + wc * 64;
    int mt16 = m0 >> 4, jt16 = j0 >> 4;

    f32x4 acc[4][4];
    #pragma unroll
    for (int a = 0; a < 4; ++a)
        #pragma unroll
        for (int b = 0; b < 4; ++b) acc[a][b] = (f32x4){0.f,0.f,0.f,0.f};

    bf16x8 af0[4], bf0[4], af1[4], bf1[4];
    auto load_ab = [&](int kc, bf16x8 (&af)[4], bf16x8 (&bf)[4]) {
        #pragma unroll
        for (int mf = 0; mf < 4; ++mf)
            af[mf] = *(const bf16x8*)(xfrag + ((size_t)((mt16 + mf) * 16 + kc) * 64 + lane) * 8);
        #pragma unroll
        for (int nt = 0; nt < 4; ++nt)
            bf[nt] = *(const bf16x8*)(wbfrag + ((size_t)((jt16 + nt) * 16 + kc) * 64 + lane) * 8);
    };
    auto do_mfma = [&](bf16x8 (&af)[4], bf16x8 (&bf)[4]) {
        #pragma unroll
        for (int mf = 0; mf < 4; ++mf)
            #pragma unroll
            for (int nt = 0; nt < 4; ++nt)
                acc[mf][nt] = __builtin_amdgcn_mfma_f32_16x16x32_bf16(af[mf], bf[nt], acc[mf][nt], 0, 0, 0);
    };

    load_ab(0, af0, bf0);
    for (int kc = 0; kc < 16; kc += 2) {
        load_ab(kc + 1, af1, bf1);
        do_mfma(af0, bf0);
        load_ab((kc + 2) & 15, af0, bf0);   // phantom wrap reload on last iter
        do_mfma(af1, bf1);
    }

    int part = j0 >> 9;            // 0=q,1=k,2=v
    int h = (j0 & 511) >> 6;
    int b_ = m0 >> 11, tloc = m0 & (T - 1);
    int bh = b_ * NH + h;
    float bcol[4];
    #pragma unroll
    for (int nt = 0; nt < 4; ++nt) bcol[nt] = bias[j0 + nt * 16 + lm];

    if (part == 2) {
        // LDS [dh][key]; C-layout r-runs are contiguous keys -> b64 writes
        #pragma unroll
        for (int mf = 0; mf < 4; ++mf)
            #pragma unroll
            for (int nt = 0; nt < 4; ++nt) {
                uint2 pw;
                pw.x = pack_bf16_pair(acc[mf][nt][0] + bcol[nt],
                                      acc[mf][nt][1] + bcol[nt]);
                pw.y = pack_bf16_pair(acc[mf][nt][2] + bcol[nt],
                                      acc[mf][nt][3] + bcol[nt]);
                *(uint2*)&Ls[wave][nt * 16 + lm][mf * 16 + quad * 4] = pw;
            }
        #pragma unroll
        for (int nt = 0; nt < 4; ++nt)
            #pragma unroll
            for (int kk = 0; kk < 2; ++kk) {
                bf16x8 fr = *(const bf16x8*)&Ls[wave][nt * 16 + lm][kk * 32 + quad * 8];
                size_t chunk = (((size_t)bh * 32 + (tloc >> 6)) * 2 + kk) * 4 + nt;
                *(bf16x8*)(vfrag + chunk * 512 + lane * 8) = fr;
            }
    } else {
        // LDS [token][dh]; scalar b16 writes (one-time), b128 frag reads
        float scale = (part == 0) ? QSCALE : 1.0f;
        #pragma unroll
        for (int mf = 0; mf < 4; ++mf)
            #pragma unroll
            for (int nt = 0; nt < 4; ++nt)
                #pragma unroll
                for (int r = 0; r < 4; ++r)
                    Ls[wave][mf * 16 + quad * 4 + r][nt * 16 + lm] =
                        f2bf((acc[mf][nt][r] + bcol[nt]) * scale);
        if (part == 0) {
            #pragma unroll
            for (int mf = 0; mf < 4; ++mf)
                #pragma unroll
                for (int kk = 0; kk < 2; ++kk) {
                    bf16x8 fr = *(const bf16x8*)&Ls[wave][mf * 16 + lm][kk * 32 + quad * 8];
                    size_t chunk = ((size_t)bh * 128 + (tloc >> 4) + mf) * 2 + kk;
                    *(bf16x8*)(qfrag + chunk * 512 + lane * 8) = fr;
                }
        } else {
            #pragma unroll
            for (int nta = 0; nta < 4; ++nta)
                #pragma unroll
                for (int kk = 0; kk < 2; ++kk) {
                    bf16x8 fr = *(const bf16x8*)&Ls[wave][lm * 4 + nta][kk * 32 + quad * 8];
                    size_t chunk = (((size_t)bh * 32 + (tloc >> 6)) * 2 + kk) * 4 + nta;
                    *(bf16x8*)(kfrag + chunk * 512 + lane * 8) = fr;
                }
        }
    }
}

// ---------------- Kernel C: flash attention, 256 queries/block --------------
// Grid 256 (1/CU): bh = g&31 (XCD-locality), q-supertile = g>>5. Each wave
// owns 64 queries; K/V fragments loaded directly from L2 as contiguous 1-KB
// bursts; K + key-bias register-double-buffered; p = exp2(s + wscaled[key]).
__global__ __launch_bounds__(256, 1) void attn_mfma(
    const unsigned short* __restrict__ qfrag, const unsigned short* __restrict__ kfrag,
    const unsigned short* __restrict__ vfrag, const float* __restrict__ wscaled,
    const float* __restrict__ kpmf, float* __restrict__ S)
{
    __shared__ __align__(16) unsigned short Ps[256][72];
    int g = blockIdx.x;
    int bh = g & 31, q0 = (g >> 5) * 256;
    int tid = threadIdx.x, wave = tid >> 6, lane = tid & 63;
    int quad = lane >> 4, lm = lane & 15;
    int b_ = bh >> 3, h = bh & 7;

    bf16x8 qf[4][2];
    int t16b = (q0 >> 4) + wave * 4;
    #pragma unroll
    for (int mf = 0; mf < 4; ++mf)
        #pragma unroll
        for (int kk = 0; kk < 2; ++kk)
            qf[mf][kk] = *(const bf16x8*)(qfrag +
                (((size_t)(bh * 128 + t16b + mf) * 2 + kk) * 64 + lane) * 8);

    f32x4 accO[4][4];
    float l_part[4][4];
    #pragma unroll
    for (int mf = 0; mf < 4; ++mf)
        #pragma unroll
        for (int nt = 0; nt < 4; ++nt) {
            accO[mf][nt] = (f32x4){0.f,0.f,0.f,0.f};
            l_part[mf][nt] = 0.f;
        }

    const unsigned short* kbase = kfrag + (size_t)bh * 32 * 8 * 512;
    const unsigned short* vbase = vfrag + (size_t)bh * 32 * 8 * 512;
    const float* wsb = wscaled + b_ * T;

    bf16x8 kf0[4][2], kf1[4][2];
    float4 b40, b41;
    auto load_k = [&](int t64, bf16x8 (&kf)[4][2], float4& b4) {
        #pragma unroll
        for (int kk = 0; kk < 2; ++kk)
            #pragma unroll
            for (int nt = 0; nt < 4; ++nt)
                kf[nt][kk] = *(const bf16x8*)(kbase +
                    ((size_t)(t64 * 2 + kk) * 4 + nt) * 512 + lane * 8);
        b4 = *(const float4*)(wsb + t64 * 64 + lm * 4);
    };

    auto process = [&](int t64, bf16x8 (&kf)[4][2], float4 b4) {
        bf16x8 vf[4][2];
        #pragma unroll
        for (int kk = 0; kk < 2; ++kk)
            #pragma unroll
            for (int nt = 0; nt < 4; ++nt)
                vf[nt][kk] = *(const bf16x8*)(vbase +
                    ((size_t)(t64 * 2 + kk) * 4 + nt) * 512 + lane * 8);

        #pragma unroll
        for (int mf = 0; mf < 4; ++mf) {
            f32x4 s[4];
            #pragma unroll
            for (int nt = 0; nt < 4; ++nt) {
                f32x4 t0 = (f32x4){0.f,0.f,0.f,0.f};
                t0 = __builtin_amdgcn_mfma_f32_16x16x32_bf16(qf[mf][0], kf[nt][0], t0, 0, 0, 0);
                t0 = __builtin_amdgcn_mfma_f32_16x16x32_bf16(qf[mf][1], kf[nt][1], t0, 0, 0, 0);
                s[nt] = t0;
            }
            int rowb = wave * 64 + mf * 16 + quad * 4;
            #pragma unroll
            for (int r = 0; r < 4; ++r) {
                float p0 = __builtin_amdgcn_exp2f(s[0][r] + b4.x);
                float p1 = __builtin_amdgcn_exp2f(s[1][r] + b4.y);
                float p2 = __builtin_amdgcn_exp2f(s[2][r] + b4.z);
                float p3 = __builtin_amdgcn_exp2f(s[3][r] + b4.w);
                l_part[mf][r] += (p0 + p1) + (p2 + p3);
                uint2 pw;
                pw.x = pack_bf16_pair(p0, p1);
                pw.y = pack_bf16_pair(p2, p3);
                *(uint2*)&Ps[rowb + r][lm * 4] = pw;
            }
        }

        bf16x8 pf[4][2];
        #pragma unroll
        for (int mf = 0; mf < 4; ++mf)
            #pragma unroll
            for (int kk = 0; kk < 2; ++kk)
                pf[mf][kk] = *(const bf16x8*)&Ps[wave * 64 + mf * 16 + lm][kk * 32 + quad * 8];

        #pragma unroll
        for (int mf = 0; mf < 4; ++mf)
            #pragma unroll
            for (int nt = 0; nt < 4; ++nt) {
                accO[mf][nt] = __builtin_amdgcn_mfma_f32_16x16x32_bf16(pf[mf][0], vf[nt][0], accO[mf][nt], 0, 0, 0);
                accO[mf][nt] = __builtin_amdgcn_mfma_f32_16x16x32_bf16(pf[mf][1], vf[nt][1], accO[mf][nt], 0, 0, 0);
            }
    };

    load_k(0, kf0, b40);
    for (int t64 = 0; t64 < 32; t64 += 2) {
        load_k(t64 + 1, kf1, b41);
        process(t64, kf0, b40);
        load_k((t64 + 2) & 31, kf0, b40);    // phantom wrap reload on last iter
        process(t64 + 1, kf1, b41);
    }

    // finish l: sum across the 16 col-owning lanes (lane bits 0..3)
    #pragma unroll
    for (int mf = 0; mf < 4; ++mf)
        #pragma unroll
        for (int r = 0; r < 4; ++r) {
            float lv = l_part[mf][r];
            #pragma unroll
            for (int off = 1; off <= 8; off <<= 1) lv += __shfl_xor(lv, off, 64);
            l_part[mf][r] = lv;
        }

    // fused masked pooling
    float pooled[4] = {0.f, 0.f, 0.f, 0.f};
    #pragma unroll
    for (int mf = 0; mf < 4; ++mf)
        #pragma unroll
        for (int r = 0; r < 4; ++r) {
            int row = q0 + wave * 64 + mf * 16 + quad * 4 + r;
            float w = (1.0f - kpmf[b_ * T + row]) / l_part[mf][r];
            #pragma unroll
            for (int nt = 0; nt < 4; ++nt) pooled[nt] += accO[mf][nt][r] * w;
        }
    #pragma unroll
    for (int nt = 0; nt < 4; ++nt) {
        pooled[nt] += __shfl_xor(pooled[nt], 16, 64);
        pooled[nt] += __shfl_xor(pooled[nt], 32, 64);
    }
    if (quad == 0) {
        #pragma unroll
        for (int nt = 0; nt < 4; ++nt)
            atomicAdd(&S[b_ * D + h * DH + nt * 16 + lm], pooled[nt]);
    }
}

// ---------------- Kernel E: out-projection of pooled vector + bias ----------
__global__ __launch_bounds__(256) void out_kernel(
    const float* __restrict__ S, const float* __restrict__ kpmf,
    const float* __restrict__ Wo, const float* __restrict__ bo,
    float* __restrict__ out)
{
    __shared__ float Sl[512];
    __shared__ float cs[4];
    __shared__ float pr[4][64];
    int b_ = blockIdx.x >> 3;
    int cg = blockIdx.x & 7;
    int tid = threadIdx.x;
    int col = tid & 63, kq = tid >> 6;
    Sl[tid] = S[b_ * D + tid];
    Sl[tid + 256] = S[b_ * D + tid + 256];
    const float* kp = kpmf + b_ * T;
    float c = 0.f;
    for (int t = tid; t < T; t += 256) c += kp[t];
    #pragma unroll
    for (int o = 32; o; o >>= 1) c += __shfl_xor(c, o, 64);
    if ((tid & 63) == 0) cs[tid >> 6] = c;
    __syncthreads();
    float masked = cs[0] + cs[1] + cs[2] + cs[3];
    float cnt = (float)T - masked;
    float inv = 1.0f / fmaxf(cnt, 1.0f);

    int d = cg * 64 + col;
    const float4* wr4 = (const float4*)(Wo + (size_t)d * D + kq * 128);
    float dot = 0.f;
    #pragma unroll 8
    for (int i = 0; i < 32; ++i) {
        float4 w4 = wr4[i];
        int kbase = kq * 128 + i * 4;
        dot += Sl[kbase + 0] * w4.x + Sl[kbase + 1] * w4.y +
               Sl[kbase + 2] * w4.z + Sl[kbase + 3] * w4.w;
    }
    pr[kq][col] = dot;
    __syncthreads();
    if (kq == 0) {
        float tot = pr[0][col] + pr[1][col] + pr[2][col] + pr[3][col];
        out[b_ * D + d] = (tot + bo[d] * cnt) * inv;
    }
}

extern "C" void kernel_launch(void* const* d_in, const int* in_sizes, int n_in,
                              void* d_out, int out_size, void* d_ws, size_t ws_size,
                              hipStream_t stream) {
    const float* embs   = (const float*)d_in[0];
    const float* labels = (const float*)d_in[1];
    const float* ln_g   = (const float*)d_in[2];
    const float* ln_b   = (const float*)d_in[3];
    const float* ipw    = (const float*)d_in[4];
    const float* ipb    = (const float*)d_in[5];
    const float* ow     = (const float*)d_in[6];
    const float* obb    = (const float*)d_in[7];
    const float* alpha  = (const float*)d_in[8];
    const float* beta   = (const float*)d_in[9];
    float* out = (float*)d_out;

    unsigned short* xfrag  = (unsigned short*)d_ws;          // 8192*512
    unsigned short* wbfrag = xfrag + (size_t)NTOK * D;       // 1536*512
    unsigned short* qfrag  = wbfrag + (size_t)3 * D * D;     // 8192*512
    unsigned short* kfrag  = qfrag + (size_t)NTOK * D;       // 8192*512
    unsigned short* vfrag  = kfrag + (size_t)NTOK * D;       // 8192*512
    float* wscaled = (float*)(vfrag + (size_t)NTOK * D);     // 8192
    float* kpmf    = wscaled + NTOK;                         // 8192
    float* S       = kpmf + NTOK;                            // 2048

    hipMemsetAsync(S, 0, (size_t)NB * D * sizeof(float), stream);
    ln_kernel<<<NTOK / 16, 256, 0, stream>>>(embs, labels, ln_g, ln_b, alpha, beta,
                                             xfrag, wscaled, kpmf);
    wconv_kernel<<<(3 * D) / 16, 256, 0, stream>>>(ipw, wbfrag);
    dim3 gq(NTOK / 128, (3 * D) / 128);
    qkv_mfma<<<gq, 256, 0, stream>>>(xfrag, wbfrag, ipb, qfrag, kfrag, vfrag);
    attn_mfma<<<256, 256, 0, stream>>>(qfrag, kfrag, vfrag, wscaled, kpmf, S);
    out_kernel<<<NB * 8, 256, 0, stream>>>(S, kpmf, ow, obb, out);
}

// Round 11
// 173.224 us; speedup vs baseline: 1.8898x; 1.0089x over previous
//
#include <hip/hip_runtime.h>
#include <math.h>

#define T 2048
#define D 512
#define NH 8
#define DH 64
#define NB 4
#define NTOK (NB * T)   // 8192
#define LOG2E 1.44269504f
#define QSCALE (0.125f * LOG2E)

using bf16x8 = __attribute__((ext_vector_type(8))) short;
using f32x4  = __attribute__((ext_vector_type(4))) float;

static __device__ __forceinline__ unsigned short f2bf(float f) {
    union { float f; unsigned u; } v; v.f = f;
    unsigned r = v.u + 0x7fffu + ((v.u >> 16) & 1u);   // RNE
    return (unsigned short)(r >> 16);
}
#if __has_builtin(__builtin_amdgcn_cvt_pk_bf16_f32)
static __device__ __forceinline__ unsigned pack_bf16_pair(float a, float b) {
    auto r = __builtin_amdgcn_cvt_pk_bf16_f32(a, b);
    union { decltype(r) v; unsigned u; } c; c.v = r;
    return c.u;
}
#else
static __device__ __forceinline__ unsigned pack_bf16_pair(float a, float b) {
    union { float f; unsigned u; } ua, ub; ua.f = a; ub.f = b;
    unsigned ra = ua.u + 0x7fffu + ((ua.u >> 16) & 1u);
    unsigned rb = ub.u + 0x7fffu + ((ub.u >> 16) & 1u);
    return __builtin_amdgcn_perm(rb, ra, 0x07060302);
}
#endif

// Fragment layouts (lane = quad*16+lm, 8 bf16 per lane, 1 KB per chunk):
// xfrag  A-frag: chunk = t16*16 + kc           elem = x[t16*16+lm][kc*32+quad*8+e]
// wbfrag B-frag: chunk = j16*16 + kc           elem = W[j16*16+lm][kc*32+quad*8+e]
// qfrag  A-frag: chunk = (bh*128+t16)*2+kk     elem = q[t16*16+lm][kk*32+quad*8+e]
// kfrag  B-frag: chunk = ((bh*32+t64)*2+kk)*4+nt  elem = k[key=t64*64+lm*4+nt][kk*32+quad*8+e]
// vfrag  B-frag: chunk = ((bh*32+t64)*2+kk)*5+nt  elem = v'[dh=nt*16+lm][key=t64*64+kk*32+quad*8+e]
//        (nt=4 column of vfrag = w-vector for l-via-MFMA; v' = w*v)

// ---------------- Kernel A: LayerNorm -> A-fragment-order x -----------------
// wexp[n] = exp(alpha*label+beta), or 0 if masked.
__global__ __launch_bounds__(256) void ln_kernel(
    const float* __restrict__ embs, const float* __restrict__ labels,
    const float* __restrict__ g, const float* __restrict__ bb,
    const float* __restrict__ alpha_p, const float* __restrict__ beta_p,
    unsigned short* __restrict__ xfrag, float* __restrict__ wexp,
    float* __restrict__ kpmf)
{
    __shared__ __align__(16) unsigned short Xs[16][520];
    int tid = threadIdx.x, wave = tid >> 6, lane = tid & 63;
    int quad = lane >> 4, lm = lane & 15;
    int t16 = blockIdx.x;

    float4 g0 = *(const float4*)(g + lane * 8), g1 = *(const float4*)(g + lane * 8 + 4);
    float4 c0 = *(const float4*)(bb + lane * 8), c1 = *(const float4*)(bb + lane * 8 + 4);
    float gv[8] = {g0.x, g0.y, g0.z, g0.w, g1.x, g1.y, g1.z, g1.w};
    float cv[8] = {c0.x, c0.y, c0.z, c0.w, c1.x, c1.y, c1.z, c1.w};

    for (int tt = 0; tt < 4; ++tt) {
        int n = t16 * 16 + wave * 4 + tt;
        const float* e = embs + (size_t)n * D + lane * 8;
        float4 a4 = *(const float4*)e, b4 = *(const float4*)(e + 4);
        float v[8] = {a4.x, a4.y, a4.z, a4.w, b4.x, b4.y, b4.z, b4.w};

        float s = 0.f, ss = 0.f;
        #pragma unroll
        for (int j = 0; j < 8; ++j) { s += v[j]; ss += v[j] * v[j]; }
        #pragma unroll
        for (int o = 1; o <= 32; o <<= 1) {
            s += __shfl_xor(s, o, 64);
            ss += __shfl_xor(ss, o, 64);
        }
        float mu = s * (1.0f / D);
        float var = ss * (1.0f / D) - mu * mu;
        float rstd = rsqrtf(var + 1e-5f);

        float x[8], as = 0.f;
        #pragma unroll
        for (int j = 0; j < 8; ++j) {
            x[j] = (v[j] - mu) * rstd * gv[j] + cv[j];
            as += fabsf(x[j]);
        }
        uint4 pk;
        pk.x = pack_bf16_pair(x[0], x[1]);
        pk.y = pack_bf16_pair(x[2], x[3]);
        pk.z = pack_bf16_pair(x[4], x[5]);
        pk.w = pack_bf16_pair(x[6], x[7]);
        *(uint4*)&Xs[wave * 4 + tt][lane * 8] = pk;

        #pragma unroll
        for (int o = 1; o <= 32; o <<= 1) as += __shfl_xor(as, o, 64);
        if (lane == 0) {
            int kpm = (as <= 1e-6f);
            kpmf[n] = kpm ? 1.0f : 0.0f;
            wexp[n] = kpm ? 0.0f : __expf(alpha_p[0] * labels[n] + beta_p[0]);
        }
    }
    __syncthreads();
    #pragma unroll
    for (int i = 0; i < 4; ++i) {
        int kc = wave * 4 + i;
        bf16x8 fr = *(const bf16x8*)&Xs[lm][kc * 32 + quad * 8];
        *(bf16x8*)(xfrag + ((size_t)(t16 * 16 + kc) * 64 + lane) * 8) = fr;
    }
}

// ---------------- W -> bf16 B-fragment order --------------------------------
__global__ __launch_bounds__(256) void wconv_kernel(
    const float* __restrict__ w, unsigned short* __restrict__ wbfrag)
{
    __shared__ __align__(16) unsigned short Ws[16][520];
    int tid = threadIdx.x, wave = tid >> 6, lane = tid & 63;
    int quad = lane >> 4, lm = lane & 15;
    int j16 = blockIdx.x;

    for (int tt = 0; tt < 4; ++tt) {
        int j = j16 * 16 + wave * 4 + tt;
        const float* wp = w + (size_t)j * D + lane * 8;
        float4 a4 = *(const float4*)wp, b4 = *(const float4*)(wp + 4);
        uint4 pk;
        pk.x = pack_bf16_pair(a4.x, a4.y);
        pk.y = pack_bf16_pair(a4.z, a4.w);
        pk.z = pack_bf16_pair(b4.x, b4.y);
        pk.w = pack_bf16_pair(b4.z, b4.w);
        *(uint4*)&Ws[wave * 4 + tt][lane * 8] = pk;
    }
    __syncthreads();
    #pragma unroll
    for (int i = 0; i < 4; ++i) {
        int kc = wave * 4 + i;
        bf16x8 fr = *(const bf16x8*)&Ws[lm][kc * 32 + quad * 8];
        *(bf16x8*)(wbfrag + ((size_t)(j16 * 16 + kc) * 64 + lane) * 8) = fr;
    }
}

// ---------------- wfrag fill: V-fragment nt=4 column = w --------------------
__global__ __launch_bounds__(256) void wfrag_fill(
    const float* __restrict__ wexp, unsigned short* __restrict__ vfrag)
{
    int idx = blockIdx.x * 256 + threadIdx.x;   // 0..131071
    int lane = idx & 63, chunk = idx >> 6;      // chunk = (bh*32+t64)*2+kk
    int kk = chunk & 1, t64 = (chunk >> 1) & 31, bh = chunk >> 6;
    int lm = lane & 15, quad = lane >> 4;
    int b_ = bh >> 3;
    size_t base = (((size_t)chunk * 5 + 4) * 64 + lane) * 8;
    if (lm == 0) {
        int key0 = t64 * 64 + kk * 32 + quad * 8;
        const float* wp = wexp + b_ * T + key0;
        unsigned short vv[8];
        #pragma unroll
        for (int e = 0; e < 8; ++e) vv[e] = f2bf(wp[e]);
        *(uint4*)(vfrag + base) = *(uint4*)vv;
    } else {
        uint4 z = {0u, 0u, 0u, 0u};
        *(uint4*)(vfrag + base) = z;
    }
}

// ---------------- Kernel B: QKV projection, all-coalesced, pipelined --------
__global__ __launch_bounds__(256) void qkv_mfma(
    const unsigned short* __restrict__ xfrag, const unsigned short* __restrict__ wbfrag,
    const float* __restrict__ bias, const float* __restrict__ wexp,
    unsigned short* __restrict__ qfrag, unsigned short* __restrict__ kfrag,
    unsigned short* __restrict__ vfrag)
{
    __shared__ __align__(16) unsigned short Ls[4][64][72];
    int tid = threadIdx.x;
    int wave = tid >> 6, lane = tid & 63, quad = lane >> 4, lm = lane & 15;
    int wr = wave >> 1, wc = wave & 1;
    int m0 = blockIdx.x * 128 + wr * 64;
    int j0 = blockIdx.y * 128 + wc * 64;
    int mt16 = m0 >> 4, jt16 = j0 >> 4;

    f32x4 acc[4][4];
    #pragma unroll
    for (int a = 0; a < 4; ++a)
        #pragma unroll
        for (int b = 0; b < 4; ++b) acc[a][b] = (f32x4){0.f,0.f,0.f,0.f};

    bf16x8 af0[4], bf0[4], af1[4], bf1[4];
    auto load_ab = [&](int kc, bf16x8 (&af)[4], bf16x8 (&bf)[4]) {
        #pragma unroll
        for (int mf = 0; mf < 4; ++mf)
            af[mf] = *(const bf16x8*)(xfrag + ((size_t)((mt16 + mf) * 16 + kc) * 64 + lane) * 8);
        #pragma unroll
        for (int nt = 0; nt < 4; ++nt)
            bf[nt] = *(const bf16x8*)(wbfrag + ((size_t)((jt16 + nt) * 16 + kc) * 64 + lane) * 8);
    };
    auto do_mfma = [&](bf16x8 (&af)[4], bf16x8 (&bf)[4]) {
        #pragma unroll
        for (int mf = 0; mf < 4; ++mf)
            #pragma unroll
            for (int nt = 0; nt < 4; ++nt)
                acc[mf][nt] = __builtin_amdgcn_mfma_f32_16x16x32_bf16(af[mf], bf[nt], acc[mf][nt], 0, 0, 0);
    };

    load_ab(0, af0, bf0);
    for (int kc = 0; kc < 16; kc += 2) {
        load_ab(kc + 1, af1, bf1);
        do_mfma(af0, bf0);
        load_ab((kc + 2) & 15, af0, bf0);   // phantom wrap reload on last iter
        do_mfma(af1, bf1);
    }

    int part = j0 >> 9;            // 0=q,1=k,2=v
    int h = (j0 & 511) >> 6;
    int b_ = m0 >> 11, tloc = m0 & (T - 1);
    int bh = b_ * NH + h;
    float bcol[4];
    #pragma unroll
    for (int nt = 0; nt < 4; ++nt) bcol[nt] = bias[j0 + nt * 16 + lm];

    if (part == 2) {
        // V' = w*V; LDS [dh][key]; C-layout r-runs contiguous -> b64 writes
        float wv[4][4];
        #pragma unroll
        for (int mf = 0; mf < 4; ++mf)
            #pragma unroll
            for (int r = 0; r < 4; ++r)
                wv[mf][r] = wexp[b_ * T + tloc + mf * 16 + quad * 4 + r];
        #pragma unroll
        for (int mf = 0; mf < 4; ++mf)
            #pragma unroll
            for (int nt = 0; nt < 4; ++nt) {
                uint2 pw;
                pw.x = pack_bf16_pair((acc[mf][nt][0] + bcol[nt]) * wv[mf][0],
                                      (acc[mf][nt][1] + bcol[nt]) * wv[mf][1]);
                pw.y = pack_bf16_pair((acc[mf][nt][2] + bcol[nt]) * wv[mf][2],
                                      (acc[mf][nt][3] + bcol[nt]) * wv[mf][3]);
                *(uint2*)&Ls[wave][nt * 16 + lm][mf * 16 + quad * 4] = pw;
            }
        #pragma unroll
        for (int nt = 0; nt < 4; ++nt)
            #pragma unroll
            for (int kk = 0; kk < 2; ++kk) {
                bf16x8 fr = *(const bf16x8*)&Ls[wave][nt * 16 + lm][kk * 32 + quad * 8];
                size_t chunk = ((((size_t)bh * 32 + (tloc >> 6)) * 2 + kk) * 5) + nt;
                *(bf16x8*)(vfrag + chunk * 512 + lane * 8) = fr;
            }
    } else {
        // LDS [token][dh]; scalar b16 writes (one-time), b128 frag reads
        float scale = (part == 0) ? QSCALE : 1.0f;
        #pragma unroll
        for (int mf = 0; mf < 4; ++mf)
            #pragma unroll
            for (int nt = 0; nt < 4; ++nt)
                #pragma unroll
                for (int r = 0; r < 4; ++r)
                    Ls[wave][mf * 16 + quad * 4 + r][nt * 16 + lm] =
                        f2bf((acc[mf][nt][r] + bcol[nt]) * scale);
        if (part == 0) {
            #pragma unroll
            for (int mf = 0; mf < 4; ++mf)
                #pragma unroll
                for (int kk = 0; kk < 2; ++kk) {
                    bf16x8 fr = *(const bf16x8*)&Ls[wave][mf * 16 + lm][kk * 32 + quad * 8];
                    size_t chunk = ((size_t)bh * 128 + (tloc >> 4) + mf) * 2 + kk;
                    *(bf16x8*)(qfrag + chunk * 512 + lane * 8) = fr;
                }
        } else {
            #pragma unroll
            for (int nta = 0; nta < 4; ++nta)
                #pragma unroll
                for (int kk = 0; kk < 2; ++kk) {
                    bf16x8 fr = *(const bf16x8*)&Ls[wave][lm * 4 + nta][kk * 32 + quad * 8];
                    size_t chunk = ((((size_t)bh * 32 + (tloc >> 6)) * 2 + kk) * 4) + nta;
                    *(bf16x8*)(kfrag + chunk * 512 + lane * 8) = fr;
                }
        }
    }
}

// ---------------- Kernel C: flash attention, 128q/block, dbuf K -------------
// Grid 512 (2/CU): bh = g&31 (XCD-locality). Wave owns 32 queries.
// p = exp2(s); bias/mask folded into V'; l via MFMA w-column; pooling fused.
__global__ __launch_bounds__(256) void attn_mfma(
    const unsigned short* __restrict__ qfrag, const unsigned short* __restrict__ kfrag,
    const unsigned short* __restrict__ vfrag, const float* __restrict__ kpmf,
    float* __restrict__ S)
{
    __shared__ __align__(16) unsigned short Ps[128][72];
    int g = blockIdx.x;
    int bh = g & 31, q0 = (g >> 5) * 128;
    int tid = threadIdx.x, wave = tid >> 6, lane = tid & 63;
    int quad = lane >> 4, lm = lane & 15;
    int b_ = bh >> 3, h = bh & 7;

    bf16x8 qf[2][2];
    int t32 = (q0 >> 5) + wave;
    #pragma unroll
    for (int mf = 0; mf < 2; ++mf)
        #pragma unroll
        for (int kk = 0; kk < 2; ++kk)
            qf[mf][kk] = *(const bf16x8*)(qfrag +
                ((((size_t)(bh * 64 + t32) * 2 + mf) * 2 + kk) * 64 + lane) * 8);

    f32x4 accO[2][4], accL[2];
    #pragma unroll
    for (int mf = 0; mf < 2; ++mf) {
        #pragma unroll
        for (int nt = 0; nt < 4; ++nt) accO[mf][nt] = (f32x4){0.f,0.f,0.f,0.f};
        accL[mf] = (f32x4){0.f,0.f,0.f,0.f};
    }

    // pointer bases incl. lane offset; per-t64 strides are constant
    const unsigned short* kb = kfrag + (size_t)bh * 32 * 8 * 512 + (size_t)lane * 8;
    const unsigned short* vb = vfrag + (size_t)bh * 32 * 10 * 512 + (size_t)lane * 8;

    bf16x8 kf0[4][2], kf1[4][2];
    auto load_k = [&](int t64, bf16x8 (&kf)[4][2]) {
        const unsigned short* p = kb + (size_t)t64 * 8 * 512;
        #pragma unroll
        for (int kk = 0; kk < 2; ++kk)
            #pragma unroll
            for (int nt = 0; nt < 4; ++nt)
                kf[nt][kk] = *(const bf16x8*)(p + ((size_t)kk * 4 + nt) * 512);
    };

    auto process = [&](int t64, bf16x8 (&kf)[4][2]) {
        // V loads first: latency hides under QK MFMA + exp2 + LDS round trip
        const unsigned short* p = vb + (size_t)t64 * 10 * 512;
        bf16x8 vf[5][2];
        #pragma unroll
        for (int kk = 0; kk < 2; ++kk)
            #pragma unroll
            for (int nt = 0; nt < 5; ++nt)
                vf[nt][kk] = *(const bf16x8*)(p + ((size_t)kk * 5 + nt) * 512);

        f32x4 s[2][4];
        #pragma unroll
        for (int mf = 0; mf < 2; ++mf)
            #pragma unroll
            for (int nt = 0; nt < 4; ++nt) {
                f32x4 t0 = (f32x4){0.f,0.f,0.f,0.f};
                t0 = __builtin_amdgcn_mfma_f32_16x16x32_bf16(qf[mf][0], kf[nt][0], t0, 0, 0, 0);
                t0 = __builtin_amdgcn_mfma_f32_16x16x32_bf16(qf[mf][1], kf[nt][1], t0, 0, 0, 0);
                s[mf][nt] = t0;
            }

        #pragma unroll
        for (int mf = 0; mf < 2; ++mf) {
            int rowb = wave * 32 + mf * 16 + quad * 4;
            #pragma unroll
            for (int r = 0; r < 4; ++r) {
                float p0 = __builtin_amdgcn_exp2f(s[mf][0][r]);
                float p1 = __builtin_amdgcn_exp2f(s[mf][1][r]);
                float p2 = __builtin_amdgcn_exp2f(s[mf][2][r]);
                float p3 = __builtin_amdgcn_exp2f(s[mf][3][r]);
                uint2 pw;
                pw.x = pack_bf16_pair(p0, p1);
                pw.y = pack_bf16_pair(p2, p3);
                *(uint2*)&Ps[rowb + r][lm * 4] = pw;
            }
        }

        bf16x8 pf[2][2];
        #pragma unroll
        for (int mf = 0; mf < 2; ++mf)
            #pragma unroll
            for (int kk = 0; kk < 2; ++kk)
                pf[mf][kk] = *(const bf16x8*)&Ps[wave * 32 + mf * 16 + lm][kk * 32 + quad * 8];

        #pragma unroll
        for (int mf = 0; mf < 2; ++mf) {
            #pragma unroll
            for (int nt = 0; nt < 4; ++nt) {
                accO[mf][nt] = __builtin_amdgcn_mfma_f32_16x16x32_bf16(pf[mf][0], vf[nt][0], accO[mf][nt], 0, 0, 0);
                accO[mf][nt] = __builtin_amdgcn_mfma_f32_16x16x32_bf16(pf[mf][1], vf[nt][1], accO[mf][nt], 0, 0, 0);
            }
            accL[mf] = __builtin_amdgcn_mfma_f32_16x16x32_bf16(pf[mf][0], vf[4][0], accL[mf], 0, 0, 0);
            accL[mf] = __builtin_amdgcn_mfma_f32_16x16x32_bf16(pf[mf][1], vf[4][1], accL[mf], 0, 0, 0);
        }
    };

    load_k(0, kf0);
    for (int t64 = 0; t64 < 32; t64 += 2) {
        load_k(t64 + 1, kf1);
        process(t64, kf0);
        load_k((t64 + 2) & 31, kf0);    // phantom wrap reload on last iter
        process(t64 + 1, kf1);
    }

    // fused masked pooling: l lives in col 0 (lane lm==0 of each quad group)
    float pooled[4] = {0.f, 0.f, 0.f, 0.f};
    #pragma unroll
    for (int mf = 0; mf < 2; ++mf)
        #pragma unroll
        for (int r = 0; r < 4; ++r) {
            int row = q0 + wave * 32 + mf * 16 + quad * 4 + r;
            float l = __shfl(accL[mf][r], lane & 48, 64);
            float w = (1.0f - kpmf[b_ * T + row]) / l;
            #pragma unroll
            for (int nt = 0; nt < 4; ++nt) pooled[nt] += accO[mf][nt][r] * w;
        }
    #pragma unroll
    for (int nt = 0; nt < 4; ++nt) {
        pooled[nt] += __shfl_xor(pooled[nt], 16, 64);
        pooled[nt] += __shfl_xor(pooled[nt], 32, 64);
    }
    if (quad == 0) {
        #pragma unroll
        for (int nt = 0; nt < 4; ++nt)
            atomicAdd(&S[b_ * D + h * DH + nt * 16 + lm], pooled[nt]);
    }
}

// ---------------- Kernel E: out-projection of pooled vector + bias ----------
__global__ __launch_bounds__(256) void out_kernel(
    const float* __restrict__ S, const float* __restrict__ kpmf,
    const float* __restrict__ Wo, const float* __restrict__ bo,
    float* __restrict__ out)
{
    __shared__ float Sl[512];
    __shared__ float cs[4];
    __shared__ float pr[4][64];
    int b_ = blockIdx.x >> 3;
    int cg = blockIdx.x & 7;
    int tid = threadIdx.x;
    int col = tid & 63, kq = tid >> 6;
    Sl[tid] = S[b_ * D + tid];
    Sl[tid + 256] = S[b_ * D + tid + 256];
    const float* kp = kpmf + b_ * T;
    float c = 0.f;
    for (int t = tid; t < T; t += 256) c += kp[t];
    #pragma unroll
    for (int o = 32; o; o >>= 1) c += __shfl_xor(c, o, 64);
    if ((tid & 63) == 0) cs[tid >> 6] = c;
    __syncthreads();
    float masked = cs[0] + cs[1] + cs[2] + cs[3];
    float cnt = (float)T - masked;
    float inv = 1.0f / fmaxf(cnt, 1.0f);

    int d = cg * 64 + col;
    const float4* wr4 = (const float4*)(Wo + (size_t)d * D + kq * 128);
    float dot = 0.f;
    #pragma unroll 8
    for (int i = 0; i < 32; ++i) {
        float4 w4 = wr4[i];
        int kbase = kq * 128 + i * 4;
        dot += Sl[kbase + 0] * w4.x + Sl[kbase + 1] * w4.y +
               Sl[kbase + 2] * w4.z + Sl[kbase + 3] * w4.w;
    }
    pr[kq][col] = dot;
    __syncthreads();
    if (kq == 0) {
        float tot = pr[0][col] + pr[1][col] + pr[2][col] + pr[3][col];
        out[b_ * D + d] = (tot + bo[d] * cnt) * inv;
    }
}

extern "C" void kernel_launch(void* const* d_in, const int* in_sizes, int n_in,
                              void* d_out, int out_size, void* d_ws, size_t ws_size,
                              hipStream_t stream) {
    const float* embs   = (const float*)d_in[0];
    const float* labels = (const float*)d_in[1];
    const float* ln_g   = (const float*)d_in[2];
    const float* ln_b   = (const float*)d_in[3];
    const float* ipw    = (const float*)d_in[4];
    const float* ipb    = (const float*)d_in[5];
    const float* ow     = (const float*)d_in[6];
    const float* obb    = (const float*)d_in[7];
    const float* alpha  = (const float*)d_in[8];
    const float* beta   = (const float*)d_in[9];
    float* out = (float*)d_out;

    unsigned short* xfrag  = (unsigned short*)d_ws;          // 8192*512
    unsigned short* wbfrag = xfrag + (size_t)NTOK * D;       // 1536*512
    unsigned short* qfrag  = wbfrag + (size_t)3 * D * D;     // 8192*512
    unsigned short* kfrag  = qfrag + (size_t)NTOK * D;       // 8192*512
    unsigned short* vfrag  = kfrag + (size_t)NTOK * D;       // 32*32*2*5*512
    float* wexp = (float*)(vfrag + (size_t)32 * 32 * 2 * 5 * 512);  // 8192
    float* kpmf = wexp + NTOK;                               // 8192
    float* S    = kpmf + NTOK;                               // 2048

    hipMemsetAsync(S, 0, (size_t)NB * D * sizeof(float), stream);
    ln_kernel<<<NTOK / 16, 256, 0, stream>>>(embs, labels, ln_g, ln_b, alpha, beta,
                                             xfrag, wexp, kpmf);
    wconv_kernel<<<(3 * D) / 16, 256, 0, stream>>>(ipw, wbfrag);
    wfrag_fill<<<512, 256, 0, stream>>>(wexp, vfrag);
    dim3 gq(NTOK / 128, (3 * D) / 128);
    qkv_mfma<<<gq, 256, 0, stream>>>(xfrag, wbfrag, ipb, wexp, qfrag, kfrag, vfrag);
    attn_mfma<<<32 * (T / 128), 256, 0, stream>>>(qfrag, kfrag, vfrag, kpmf, S);
    out_kernel<<<NB * 8, 256, 0, stream>>>(S, kpmf, ow, obb, out);
}

// Round 12
// 165.677 us; speedup vs baseline: 1.9758x; 1.0455x over previous
//
#include <hip/hip_runtime.h>
#include <math.h>

#define T 2048
#define D 512
#define NH 8
#define DH 64
#define NB 4
#define NTOK (NB * T)   // 8192
#define LOG2E 1.44269504f
#define QSCALE (0.125f * LOG2E)

using bf16x8 = __attribute__((ext_vector_type(8))) short;
using f32x4  = __attribute__((ext_vector_type(4))) float;

static __device__ __forceinline__ unsigned short f2bf(float f) {
    union { float f; unsigned u; } v; v.f = f;
    unsigned r = v.u + 0x7fffu + ((v.u >> 16) & 1u);   // RNE
    return (unsigned short)(r >> 16);
}
#if __has_builtin(__builtin_amdgcn_cvt_pk_bf16_f32)
static __device__ __forceinline__ unsigned pack_bf16_pair(float a, float b) {
    auto r = __builtin_amdgcn_cvt_pk_bf16_f32(a, b);
    union { decltype(r) v; unsigned u; } c; c.v = r;
    return c.u;
}
#else
static __device__ __forceinline__ unsigned pack_bf16_pair(float a, float b) {
    union { float f; unsigned u; } ua, ub; ua.f = a; ub.f = b;
    unsigned ra = ua.u + 0x7fffu + ((ua.u >> 16) & 1u);
    unsigned rb = ub.u + 0x7fffu + ((ub.u >> 16) & 1u);
    return __builtin_amdgcn_perm(rb, ra, 0x07060302);
}
#endif

// Fragment layouts (lane = quad*16+lm, 8 bf16 per lane, 1 KB per chunk):
// xfrag  A-frag: chunk = t16*16 + kc           elem = x[t16*16+lm][kc*32+quad*8+e]
// wbfrag B-frag: chunk = j16*16 + kc           elem = W[j16*16+lm][kc*32+quad*8+e]
// qfrag  A-frag: chunk = (bh*128+t16)*2+kk     elem = q[t16*16+lm][kk*32+quad*8+e]
// kfrag  B-frag: chunk = ((bh*32+t64)*2+kk)*4+nt  elem = k[key=t64*64+lm*4+nt][kk*32+quad*8+e]
// vfrag  B-frag: chunk = ((bh*32+t64)*2+kk)*5+nt  elem = v'[dh=nt*16+lm][key=t64*64+kk*32+quad*8+e]
//        (nt=4 column of vfrag = w-vector for l-via-MFMA; v' = w*v)

// ---------------- Kernel A: LayerNorm -> A-fragment-order x -----------------
// wexp[n] = exp(alpha*label+beta), or 0 if masked.
__global__ __launch_bounds__(256) void ln_kernel(
    const float* __restrict__ embs, const float* __restrict__ labels,
    const float* __restrict__ g, const float* __restrict__ bb,
    const float* __restrict__ alpha_p, const float* __restrict__ beta_p,
    unsigned short* __restrict__ xfrag, float* __restrict__ wexp,
    float* __restrict__ kpmf)
{
    __shared__ __align__(16) unsigned short Xs[16][520];
    int tid = threadIdx.x, wave = tid >> 6, lane = tid & 63;
    int quad = lane >> 4, lm = lane & 15;
    int t16 = blockIdx.x;

    float4 g0 = *(const float4*)(g + lane * 8), g1 = *(const float4*)(g + lane * 8 + 4);
    float4 c0 = *(const float4*)(bb + lane * 8), c1 = *(const float4*)(bb + lane * 8 + 4);
    float gv[8] = {g0.x, g0.y, g0.z, g0.w, g1.x, g1.y, g1.z, g1.w};
    float cv[8] = {c0.x, c0.y, c0.z, c0.w, c1.x, c1.y, c1.z, c1.w};

    for (int tt = 0; tt < 4; ++tt) {
        int n = t16 * 16 + wave * 4 + tt;
        const float* e = embs + (size_t)n * D + lane * 8;
        float4 a4 = *(const float4*)e, b4 = *(const float4*)(e + 4);
        float v[8] = {a4.x, a4.y, a4.z, a4.w, b4.x, b4.y, b4.z, b4.w};

        float s = 0.f, ss = 0.f;
        #pragma unroll
        for (int j = 0; j < 8; ++j) { s += v[j]; ss += v[j] * v[j]; }
        #pragma unroll
        for (int o = 1; o <= 32; o <<= 1) {
            s += __shfl_xor(s, o, 64);
            ss += __shfl_xor(ss, o, 64);
        }
        float mu = s * (1.0f / D);
        float var = ss * (1.0f / D) - mu * mu;
        float rstd = rsqrtf(var + 1e-5f);

        float x[8], as = 0.f;
        #pragma unroll
        for (int j = 0; j < 8; ++j) {
            x[j] = (v[j] - mu) * rstd * gv[j] + cv[j];
            as += fabsf(x[j]);
        }
        uint4 pk;
        pk.x = pack_bf16_pair(x[0], x[1]);
        pk.y = pack_bf16_pair(x[2], x[3]);
        pk.z = pack_bf16_pair(x[4], x[5]);
        pk.w = pack_bf16_pair(x[6], x[7]);
        *(uint4*)&Xs[wave * 4 + tt][lane * 8] = pk;

        #pragma unroll
        for (int o = 1; o <= 32; o <<= 1) as += __shfl_xor(as, o, 64);
        if (lane == 0) {
            int kpm = (as <= 1e-6f);
            kpmf[n] = kpm ? 1.0f : 0.0f;
            wexp[n] = kpm ? 0.0f : __expf(alpha_p[0] * labels[n] + beta_p[0]);
        }
    }
    __syncthreads();
    #pragma unroll
    for (int i = 0; i < 4; ++i) {
        int kc = wave * 4 + i;
        bf16x8 fr = *(const bf16x8*)&Xs[lm][kc * 32 + quad * 8];
        *(bf16x8*)(xfrag + ((size_t)(t16 * 16 + kc) * 64 + lane) * 8) = fr;
    }
}

// ---------------- W -> bf16 B-fragment order --------------------------------
__global__ __launch_bounds__(256) void wconv_kernel(
    const float* __restrict__ w, unsigned short* __restrict__ wbfrag)
{
    __shared__ __align__(16) unsigned short Ws[16][520];
    int tid = threadIdx.x, wave = tid >> 6, lane = tid & 63;
    int quad = lane >> 4, lm = lane & 15;
    int j16 = blockIdx.x;

    for (int tt = 0; tt < 4; ++tt) {
        int j = j16 * 16 + wave * 4 + tt;
        const float* wp = w + (size_t)j * D + lane * 8;
        float4 a4 = *(const float4*)wp, b4 = *(const float4*)(wp + 4);
        uint4 pk;
        pk.x = pack_bf16_pair(a4.x, a4.y);
        pk.y = pack_bf16_pair(a4.z, a4.w);
        pk.z = pack_bf16_pair(b4.x, b4.y);
        pk.w = pack_bf16_pair(b4.z, b4.w);
        *(uint4*)&Ws[wave * 4 + tt][lane * 8] = pk;
    }
    __syncthreads();
    #pragma unroll
    for (int i = 0; i < 4; ++i) {
        int kc = wave * 4 + i;
        bf16x8 fr = *(const bf16x8*)&Ws[lm][kc * 32 + quad * 8];
        *(bf16x8*)(wbfrag + ((size_t)(j16 * 16 + kc) * 64 + lane) * 8) = fr;
    }
}

// ---------------- wfrag fill: V-fragment nt=4 column = w --------------------
__global__ __launch_bounds__(256) void wfrag_fill(
    const float* __restrict__ wexp, unsigned short* __restrict__ vfrag)
{
    int idx = blockIdx.x * 256 + threadIdx.x;   // 0..131071
    int lane = idx & 63, chunk = idx >> 6;      // chunk = (bh*32+t64)*2+kk
    int kk = chunk & 1, t64 = (chunk >> 1) & 31, bh = chunk >> 6;
    int lm = lane & 15, quad = lane >> 4;
    int b_ = bh >> 3;
    size_t base = (((size_t)chunk * 5 + 4) * 64 + lane) * 8;
    if (lm == 0) {
        int key0 = t64 * 64 + kk * 32 + quad * 8;
        const float* wp = wexp + b_ * T + key0;
        unsigned short vv[8];
        #pragma unroll
        for (int e = 0; e < 8; ++e) vv[e] = f2bf(wp[e]);
        *(uint4*)(vfrag + base) = *(uint4*)vv;
    } else {
        uint4 z = {0u, 0u, 0u, 0u};
        *(uint4*)(vfrag + base) = z;
    }
}

// ---------------- Kernel B: QKV projection, all-coalesced, pipelined --------
__global__ __launch_bounds__(256) void qkv_mfma(
    const unsigned short* __restrict__ xfrag, const unsigned short* __restrict__ wbfrag,
    const float* __restrict__ bias, const float* __restrict__ wexp,
    unsigned short* __restrict__ qfrag, unsigned short* __restrict__ kfrag,
    unsigned short* __restrict__ vfrag)
{
    __shared__ __align__(16) unsigned short Ls[4][64][72];
    int tid = threadIdx.x;
    int wave = tid >> 6, lane = tid & 63, quad = lane >> 4, lm = lane & 15;
    int wr = wave >> 1, wc = wave & 1;
    int m0 = blockIdx.x * 128 + wr * 64;
    int j0 = blockIdx.y * 128 + wc * 64;
    int mt16 = m0 >> 4, jt16 = j0 >> 4;

    f32x4 acc[4][4];
    #pragma unroll
    for (int a = 0; a < 4; ++a)
        #pragma unroll
        for (int b = 0; b < 4; ++b) acc[a][b] = (f32x4){0.f,0.f,0.f,0.f};

    bf16x8 af0[4], bf0[4], af1[4], bf1[4];
    auto load_ab = [&](int kc, bf16x8 (&af)[4], bf16x8 (&bf)[4]) {
        #pragma unroll
        for (int mf = 0; mf < 4; ++mf)
            af[mf] = *(const bf16x8*)(xfrag + ((size_t)((mt16 + mf) * 16 + kc) * 64 + lane) * 8);
        #pragma unroll
        for (int nt = 0; nt < 4; ++nt)
            bf[nt] = *(const bf16x8*)(wbfrag + ((size_t)((jt16 + nt) * 16 + kc) * 64 + lane) * 8);
    };
    auto do_mfma = [&](bf16x8 (&af)[4], bf16x8 (&bf)[4]) {
        #pragma unroll
        for (int mf = 0; mf < 4; ++mf)
            #pragma unroll
            for (int nt = 0; nt < 4; ++nt)
                acc[mf][nt] = __builtin_amdgcn_mfma_f32_16x16x32_bf16(af[mf], bf[nt], acc[mf][nt], 0, 0, 0);
    };

    load_ab(0, af0, bf0);
    for (int kc = 0; kc < 16; kc += 2) {
        load_ab(kc + 1, af1, bf1);
        do_mfma(af0, bf0);
        load_ab((kc + 2) & 15, af0, bf0);   // phantom wrap reload on last iter
        do_mfma(af1, bf1);
    }

    int part = j0 >> 9;            // 0=q,1=k,2=v
    int h = (j0 & 511) >> 6;
    int b_ = m0 >> 11, tloc = m0 & (T - 1);
    int bh = b_ * NH + h;
    float bcol[4];
    #pragma unroll
    for (int nt = 0; nt < 4; ++nt) bcol[nt] = bias[j0 + nt * 16 + lm];

    if (part == 2) {
        // V' = w*V; LDS [dh][key]; C-layout r-runs contiguous -> b64 writes
        float wv[4][4];
        #pragma unroll
        for (int mf = 0; mf < 4; ++mf)
            #pragma unroll
            for (int r = 0; r < 4; ++r)
                wv[mf][r] = wexp[b_ * T + tloc + mf * 16 + quad * 4 + r];
        #pragma unroll
        for (int mf = 0; mf < 4; ++mf)
            #pragma unroll
            for (int nt = 0; nt < 4; ++nt) {
                uint2 pw;
                pw.x = pack_bf16_pair((acc[mf][nt][0] + bcol[nt]) * wv[mf][0],
                                      (acc[mf][nt][1] + bcol[nt]) * wv[mf][1]);
                pw.y = pack_bf16_pair((acc[mf][nt][2] + bcol[nt]) * wv[mf][2],
                                      (acc[mf][nt][3] + bcol[nt]) * wv[mf][3]);
                *(uint2*)&Ls[wave][nt * 16 + lm][mf * 16 + quad * 4] = pw;
            }
        #pragma unroll
        for (int nt = 0; nt < 4; ++nt)
            #pragma unroll
            for (int kk = 0; kk < 2; ++kk) {
                bf16x8 fr = *(const bf16x8*)&Ls[wave][nt * 16 + lm][kk * 32 + quad * 8];
                size_t chunk = ((((size_t)bh * 32 + (tloc >> 6)) * 2 + kk) * 5) + nt;
                *(bf16x8*)(vfrag + chunk * 512 + lane * 8) = fr;
            }
    } else {
        // LDS [token][dh]; scalar b16 writes (one-time), b128 frag reads
        float scale = (part == 0) ? QSCALE : 1.0f;
        #pragma unroll
        for (int mf = 0; mf < 4; ++mf)
            #pragma unroll
            for (int nt = 0; nt < 4; ++nt)
                #pragma unroll
                for (int r = 0; r < 4; ++r)
                    Ls[wave][mf * 16 + quad * 4 + r][nt * 16 + lm] =
                        f2bf((acc[mf][nt][r] + bcol[nt]) * scale);
        if (part == 0) {
            #pragma unroll
            for (int mf = 0; mf < 4; ++mf)
                #pragma unroll
                for (int kk = 0; kk < 2; ++kk) {
                    bf16x8 fr = *(const bf16x8*)&Ls[wave][mf * 16 + lm][kk * 32 + quad * 8];
                    size_t chunk = ((size_t)bh * 128 + (tloc >> 4) + mf) * 2 + kk;
                    *(bf16x8*)(qfrag + chunk * 512 + lane * 8) = fr;
                }
        } else {
            #pragma unroll
            for (int nta = 0; nta < 4; ++nta)
                #pragma unroll
                for (int kk = 0; kk < 2; ++kk) {
                    bf16x8 fr = *(const bf16x8*)&Ls[wave][lm * 4 + nta][kk * 32 + quad * 8];
                    size_t chunk = ((((size_t)bh * 32 + (tloc >> 6)) * 2 + kk) * 4) + nta;
                    *(bf16x8*)(kfrag + chunk * 512 + lane * 8) = fr;
                }
        }
    }
}

// ---------------- Kernel C: flash attention, 2x2 wave specialization --------
// Grid 512 (2/CU): bh = g&31 (XCD-locality), 128 q per block. Wave w owns
// q-half qh=w>>1 (64 queries) x key-half ks=w&1 (1024 keys): per-wave K/V
// bytes halve vs all-keys-per-wave. Max-free exp2 softmax makes partial l
// additive: one end-of-kernel LDS exchange combines the key-halves.
__global__ __launch_bounds__(256, 2) void attn_mfma(
    const unsigned short* __restrict__ qfrag, const unsigned short* __restrict__ kfrag,
    const unsigned short* __restrict__ vfrag, const float* __restrict__ kpmf,
    float* __restrict__ S)
{
    __shared__ __align__(16) unsigned short Ps[4][64][72];   // per-wave P
    __shared__ float Lx[2][2][64];                           // [qh][ks][row]
    int g = blockIdx.x;
    int bh = g & 31, q0 = (g >> 5) * 128;
    int tid = threadIdx.x, wave = tid >> 6, lane = tid & 63;
    int quad = lane >> 4, lm = lane & 15;
    int qh = wave >> 1, ks = wave & 1;
    int qbase = q0 + qh * 64;
    int b_ = bh >> 3, h = bh & 7;

    bf16x8 qf[4][2];
    int t16b = (qbase >> 4);
    #pragma unroll
    for (int mf = 0; mf < 4; ++mf)
        #pragma unroll
        for (int kk = 0; kk < 2; ++kk)
            qf[mf][kk] = *(const bf16x8*)(qfrag +
                (((size_t)(bh * 128 + t16b + mf) * 2 + kk) * 64 + lane) * 8);

    f32x4 accO[4][4], accL[4];
    #pragma unroll
    for (int mf = 0; mf < 4; ++mf) {
        #pragma unroll
        for (int nt = 0; nt < 4; ++nt) accO[mf][nt] = (f32x4){0.f,0.f,0.f,0.f};
        accL[mf] = (f32x4){0.f,0.f,0.f,0.f};
    }

    const unsigned short* kb = kfrag + (size_t)bh * 32 * 8 * 512 + (size_t)lane * 8;
    const unsigned short* vb = vfrag + (size_t)bh * 32 * 10 * 512 + (size_t)lane * 8;
    int t0k = ks * 16;   // wave's 16 key-tiles

    bf16x8 kf0[4][2], kf1[4][2];
    auto load_k = [&](int t64, bf16x8 (&kf)[4][2]) {
        const unsigned short* p = kb + (size_t)t64 * 8 * 512;
        #pragma unroll
        for (int kk = 0; kk < 2; ++kk)
            #pragma unroll
            for (int nt = 0; nt < 4; ++nt)
                kf[nt][kk] = *(const bf16x8*)(p + ((size_t)kk * 4 + nt) * 512);
    };

    auto process = [&](int t64, bf16x8 (&kf)[4][2]) {
        const unsigned short* p = vb + (size_t)t64 * 10 * 512;
        bf16x8 vf[5][2];
        #pragma unroll
        for (int kk = 0; kk < 2; ++kk)
            #pragma unroll
            for (int nt = 0; nt < 5; ++nt)
                vf[nt][kk] = *(const bf16x8*)(p + ((size_t)kk * 5 + nt) * 512);

        #pragma unroll
        for (int mf = 0; mf < 4; ++mf) {
            f32x4 s[4];
            #pragma unroll
            for (int nt = 0; nt < 4; ++nt) {
                f32x4 t0 = (f32x4){0.f,0.f,0.f,0.f};
                t0 = __builtin_amdgcn_mfma_f32_16x16x32_bf16(qf[mf][0], kf[nt][0], t0, 0, 0, 0);
                t0 = __builtin_amdgcn_mfma_f32_16x16x32_bf16(qf[mf][1], kf[nt][1], t0, 0, 0, 0);
                s[nt] = t0;
            }
            int rowb = mf * 16 + quad * 4;
            #pragma unroll
            for (int r = 0; r < 4; ++r) {
                float p0 = __builtin_amdgcn_exp2f(s[0][r]);
                float p1 = __builtin_amdgcn_exp2f(s[1][r]);
                float p2 = __builtin_amdgcn_exp2f(s[2][r]);
                float p3 = __builtin_amdgcn_exp2f(s[3][r]);
                uint2 pw;
                pw.x = pack_bf16_pair(p0, p1);
                pw.y = pack_bf16_pair(p2, p3);
                *(uint2*)&Ps[wave][rowb + r][lm * 4] = pw;
            }
        }

        bf16x8 pf[4][2];
        #pragma unroll
        for (int mf = 0; mf < 4; ++mf)
            #pragma unroll
            for (int kk = 0; kk < 2; ++kk)
                pf[mf][kk] = *(const bf16x8*)&Ps[wave][mf * 16 + lm][kk * 32 + quad * 8];

        #pragma unroll
        for (int mf = 0; mf < 4; ++mf) {
            #pragma unroll
            for (int nt = 0; nt < 4; ++nt) {
                accO[mf][nt] = __builtin_amdgcn_mfma_f32_16x16x32_bf16(pf[mf][0], vf[nt][0], accO[mf][nt], 0, 0, 0);
                accO[mf][nt] = __builtin_amdgcn_mfma_f32_16x16x32_bf16(pf[mf][1], vf[nt][1], accO[mf][nt], 0, 0, 0);
            }
            accL[mf] = __builtin_amdgcn_mfma_f32_16x16x32_bf16(pf[mf][0], vf[4][0], accL[mf], 0, 0, 0);
            accL[mf] = __builtin_amdgcn_mfma_f32_16x16x32_bf16(pf[mf][1], vf[4][1], accL[mf], 0, 0, 0);
        }
    };

    load_k(t0k, kf0);
    for (int i = 0; i < 16; i += 2) {
        load_k(t0k + i + 1, kf1);
        process(t0k + i, kf0);
        load_k(t0k + ((i + 2) & 15), kf0);   // phantom wrap reload on last iter
        process(t0k + i + 1, kf1);
    }

    // exchange partial l across the key-half pair (one barrier total)
    if (lm == 0) {
        #pragma unroll
        for (int mf = 0; mf < 4; ++mf)
            #pragma unroll
            for (int r = 0; r < 4; ++r)
                Lx[qh][ks][mf * 16 + quad * 4 + r] = accL[mf][r];
    }
    __syncthreads();

    // fused masked pooling with full l
    float pooled[4] = {0.f, 0.f, 0.f, 0.f};
    #pragma unroll
    for (int mf = 0; mf < 4; ++mf)
        #pragma unroll
        for (int r = 0; r < 4; ++r) {
            int rloc = mf * 16 + quad * 4 + r;
            float l = Lx[qh][0][rloc] + Lx[qh][1][rloc];
            float w = (1.0f - kpmf[b_ * T + qbase + rloc]) / l;
            #pragma unroll
            for (int nt = 0; nt < 4; ++nt) pooled[nt] += accO[mf][nt][r] * w;
        }
    #pragma unroll
    for (int nt = 0; nt < 4; ++nt) {
        pooled[nt] += __shfl_xor(pooled[nt], 16, 64);
        pooled[nt] += __shfl_xor(pooled[nt], 32, 64);
    }
    if (quad == 0) {
        #pragma unroll
        for (int nt = 0; nt < 4; ++nt)
            atomicAdd(&S[b_ * D + h * DH + nt * 16 + lm], pooled[nt]);
    }
}

// ---------------- Kernel E: out-projection of pooled vector + bias ----------
__global__ __launch_bounds__(256) void out_kernel(
    const float* __restrict__ S, const float* __restrict__ kpmf,
    const float* __restrict__ Wo, const float* __restrict__ bo,
    float* __restrict__ out)
{
    __shared__ float Sl[512];
    __shared__ float cs[4];
    __shared__ float pr[4][64];
    int b_ = blockIdx.x >> 3;
    int cg = blockIdx.x & 7;
    int tid = threadIdx.x;
    int col = tid & 63, kq = tid >> 6;
    Sl[tid] = S[b_ * D + tid];
    Sl[tid + 256] = S[b_ * D + tid + 256];
    const float* kp = kpmf + b_ * T;
    float c = 0.f;
    for (int t = tid; t < T; t += 256) c += kp[t];
    #pragma unroll
    for (int o = 32; o; o >>= 1) c += __shfl_xor(c, o, 64);
    if ((tid & 63) == 0) cs[tid >> 6] = c;
    __syncthreads();
    float masked = cs[0] + cs[1] + cs[2] + cs[3];
    float cnt = (float)T - masked;
    float inv = 1.0f / fmaxf(cnt, 1.0f);

    int d = cg * 64 + col;
    const float4* wr4 = (const float4*)(Wo + (size_t)d * D + kq * 128);
    float dot = 0.f;
    #pragma unroll 8
    for (int i = 0; i < 32; ++i) {
        float4 w4 = wr4[i];
        int kbase = kq * 128 + i * 4;
        dot += Sl[kbase + 0] * w4.x + Sl[kbase + 1] * w4.y +
               Sl[kbase + 2] * w4.z + Sl[kbase + 3] * w4.w;
    }
    pr[kq][col] = dot;
    __syncthreads();
    if (kq == 0) {
        float tot = pr[0][col] + pr[1][col] + pr[2][col] + pr[3][col];
        out[b_ * D + d] = (tot + bo[d] * cnt) * inv;
    }
}

extern "C" void kernel_launch(void* const* d_in, const int* in_sizes, int n_in,
                              void* d_out, int out_size, void* d_ws, size_t ws_size,
                              hipStream_t stream) {
    const float* embs   = (const float*)d_in[0];
    const float* labels = (const float*)d_in[1];
    const float* ln_g   = (const float*)d_in[2];
    const float* ln_b   = (const float*)d_in[3];
    const float* ipw    = (const float*)d_in[4];
    const float* ipb    = (const float*)d_in[5];
    const float* ow     = (const float*)d_in[6];
    const float* obb    = (const float*)d_in[7];
    const float* alpha  = (const float*)d_in[8];
    const float* beta   = (const float*)d_in[9];
    float* out = (float*)d_out;

    unsigned short* xfrag  = (unsigned short*)d_ws;          // 8192*512
    unsigned short* wbfrag = xfrag + (size_t)NTOK * D;       // 1536*512
    unsigned short* qfrag  = wbfrag + (size_t)3 * D * D;     // 8192*512
    unsigned short* kfrag  = qfrag + (size_t)NTOK * D;       // 8192*512
    unsigned short* vfrag  = kfrag + (size_t)NTOK * D;       // 32*32*2*5*512
    float* wexp = (float*)(vfrag + (size_t)32 * 32 * 2 * 5 * 512);  // 8192
    float* kpmf = wexp + NTOK;                               // 8192
    float* S    = kpmf + NTOK;                               // 2048

    hipMemsetAsync(S, 0, (size_t)NB * D * sizeof(float), stream);
    ln_kernel<<<NTOK / 16, 256, 0, stream>>>(embs, labels, ln_g, ln_b, alpha, beta,
                                             xfrag, wexp, kpmf);
    wconv_kernel<<<(3 * D) / 16, 256, 0, stream>>>(ipw, wbfrag);
    wfrag_fill<<<512, 256, 0, stream>>>(wexp, vfrag);
    dim3 gq(NTOK / 128, (3 * D) / 128);
    qkv_mfma<<<gq, 256, 0, stream>>>(xfrag, wbfrag, ipb, wexp, qfrag, kfrag, vfrag);
    attn_mfma<<<32 * (T / 128), 256, 0, stream>>>(qfrag, kfrag, vfrag, kpmf, S);
    out_kernel<<<NB * 8, 256, 0, stream>>>(S, kpmf, ow, obb, out);
}